// Round 8
// baseline (393.656 us; speedup 1.0000x reference)
//
#include <hip/hip_runtime.h>
#include <hip/hip_cooperative_groups.h>

namespace cg = cooperative_groups;

// Problem constants (from reference)
#define N_NODES 20000
#define F_IN    512
#define D_H     256
#define E_EDGES 200000
#define L_LAYERS 3
#define T_ETYPES 2
#define NBANDS  157   // ceil(20000/128)
#define M_PAD   (NBANDS * 128)   // 20096

typedef __attribute__((ext_vector_type(8))) short bf16x8;
typedef __attribute__((ext_vector_type(4))) float f32x4;
typedef unsigned short u16;

__device__ __forceinline__ u16 f2b(float f) {
    unsigned int u = __float_as_uint(f);
    u = (u + 0x7FFFu + ((u >> 16) & 1u)) >> 16;   // round-nearest-even
    return (u16)u;
}
__device__ __forceinline__ unsigned int pack2(float a, float b) {
    return (unsigned int)f2b(a) | ((unsigned int)f2b(b) << 16);
}

// async global->LDS, 16B per lane; LDS dest = wave-uniform base + lane*16.
__device__ __forceinline__ void gload16(const u16* g, u16* l)
{
    __builtin_amdgcn_global_load_lds(
        (const __attribute__((address_space(1))) void*)g,
        (__attribute__((address_space(3))) void*)l, 16, 0, 0);
}

// Fragment-slab layout (weights B-side and activations A-side):
// matrix [R, K] -> band (r>>7) x kslab (k>>5), each slab 4096 elems (8KB);
// inside: elem (r_local, kk) at ((r_local>>4)&7)<<9 | ((kk>>3)&3)<<7
//        | (r_local&15)<<3 | (kk&7).
__device__ __forceinline__ size_t slab_addr(int row, int col, int kslabs)
{
    return ((size_t)(row >> 7) * kslabs + (col >> 5)) * 4096
         + (((row >> 4) & 7) << 9) + (((col >> 3) & 3) << 7)
         + ((row & 15) << 3) + (col & 7);
}

// ---------------- prep: fp32 row-major [Mreal,K] -> bf16 slab order ----------------
__device__ __forceinline__ void shufg8(const float* __restrict__ s,
                                       u16* __restrict__ d,
                                       int NO, int Mreal, int K, int o8)
{
    const int matsz8 = (NO * K) >> 3;
    const int mat = o8 / matsz8;
    const int rem = o8 - mat * matsz8;
    const int dst = rem << 3;
    const int slab = dst >> 12;
    const int w = dst & 4095;
    const int spr = K >> 5;                    // kslabs per band
    const int slab_n = slab / spr, slab_k = slab - slab_n * spr;
    int row = slab_n * 128 + (((w >> 9) & 7) << 4) + ((w >> 3) & 15);
    if (row >= Mreal) row = Mreal - 1;
    const int kk = ((w >> 7) & 3) << 3;
    const size_t soff = (size_t)mat * Mreal * K + (size_t)row * K + slab_k * 32 + kk;
    const float4 a = *(const float4*)(s + soff);
    const float4 b = *(const float4*)(s + soff + 4);
    uint4 u;
    u.x = pack2(a.x, a.y); u.y = pack2(a.z, a.w);
    u.z = pack2(b.x, b.y); u.w = pack2(b.z, b.w);
    *(uint4*)(d + (size_t)mat * NO * K + dst) = u;
}

__global__ __launch_bounds__(256) void prep_kernel(
    const float* __restrict__ x,  u16* __restrict__ xb, int nx8,
    const float* __restrict__ s0, u16* __restrict__ d0, int NO0, int K0, int n08,
    const float* __restrict__ s1, u16* __restrict__ d1, int NO1, int K1, int n18,
    const float* __restrict__ s2, u16* __restrict__ d2, int NO2, int K2, int n28,
    const float* __restrict__ s3, u16* __restrict__ d3, int NO3, int K3, int n38)
{
    int i = blockIdx.x * 256 + threadIdx.x;
    if (i < nx8) { shufg8(x, xb, M_PAD, N_NODES, F_IN, i); return; }
    i -= nx8;
    if (i < n08) { shufg8(s0, d0, NO0, NO0, K0, i); return; }
    if ((i -= n08) < n18) { shufg8(s1, d1, NO1, NO1, K1, i); return; }
    if ((i -= n18) < n28) { shufg8(s2, d2, NO2, NO2, K2, i); return; }
    if ((i -= n28) < n38) { shufg8(s3, d3, NO3, NO3, K3, i); return; }
}

// ================= device-stage functions (shared by mega + fallback) ==============

// GEMM: 512-thr, slab-A + slab-B, counted-vmcnt, XCD swizzle. Block 128x128,
// 8 waves 2x4, wave 64x32. Block-stride over nid tile ids.
template <int NSTEPS, int CS, int SLABOUT>
__device__ __forceinline__ void dev_gemm(
    const u16* __restrict__ A, const u16* __restrict__ Wf,
    const float* __restrict__ bias, u16* __restrict__ Cout,
    int ldc, int relu, int nid, int grid, int bid,
    u16 (*As)[4096], u16 (*Bs)[4096])
{
    const int tid = threadIdx.x, lane = tid & 63;
    const int w = tid >> 6, wm = w >> 2, wn = w & 3;
    for (int id = bid; id < nid; id += grid) {
        const int g = id / (8 * CS), rem = id - g * (8 * CS);
        const int cs = rem >> 3, bmi = (g << 3) | (rem & 7);
        if (bmi < NBANDS) {
            const int bm = bmi * 128;
            const u16* abase = A + (((size_t)bmi * NSTEPS) << 12) + (size_t)tid * 8;
            const u16* bsrc = Wf + (((size_t)cs * NSTEPS) << 12) + (size_t)tid * 8;
            const int cbase = cs * 128 + wn * 32 + (lane & 15);
            float bj0 = bias[cbase], bj1 = bias[cbase + 16];
            asm volatile("" ::: "memory");
            f32x4 acc[4][2] = {};
            gload16(abase, &As[0][(size_t)tid * 8]);
            gload16(bsrc, &Bs[0][(size_t)tid * 8]);
            gload16(abase + 4096, &As[1][(size_t)tid * 8]);
            gload16(bsrc + 4096, &Bs[1][(size_t)tid * 8]);
#pragma unroll
            for (int s = 0; s < NSTEPS; ++s) {
                if (s + 1 < NSTEPS) asm volatile("s_waitcnt vmcnt(2)" ::: "memory");
                else                asm volatile("s_waitcnt vmcnt(0)" ::: "memory");
                __builtin_amdgcn_s_barrier();
                asm volatile("" ::: "memory");
                if (s + 2 < NSTEPS) {
                    gload16(abase + (((size_t)(s + 2)) << 12), &As[(s + 2) % 3][(size_t)tid * 8]);
                    gload16(bsrc + (((size_t)(s + 2)) << 12), &Bs[(s + 2) % 3][(size_t)tid * 8]);
                }
                const int buf = s % 3;
                bf16x8 av[4], bv[2];
#pragma unroll
                for (int mi = 0; mi < 4; ++mi)
                    av[mi] = *(const bf16x8*)((const char*)As[buf] + ((wm * 4 + mi) << 10) + lane * 16);
#pragma unroll
                for (int j = 0; j < 2; ++j)
                    bv[j] = *(const bf16x8*)((const char*)Bs[buf] + ((wn * 2 + j) << 10) + lane * 16);
#pragma unroll
                for (int mi = 0; mi < 4; ++mi)
#pragma unroll
                    for (int j = 0; j < 2; ++j)
                        acc[mi][j] = __builtin_amdgcn_mfma_f32_16x16x32_bf16(av[mi], bv[j], acc[mi][j], 0, 0, 0);
            }
            // C/D layout: col = lane&15, row = (lane>>4)*4 + reg
            const int rb = bm + wm * 64 + ((lane >> 4) << 2);
#pragma unroll
            for (int j = 0; j < 2; ++j) {
                const float bj = j ? bj1 : bj0;
#pragma unroll
                for (int mi = 0; mi < 4; ++mi)
#pragma unroll
                    for (int r = 0; r < 4; ++r) {
                        const int row = rb + mi * 16 + r;
                        if (row < N_NODES) {
                            float v = acc[mi][j][r] + bj;
                            if (relu) v = fmaxf(v, 0.f);
                            if (SLABOUT)
                                Cout[slab_addr(row, cbase + j * 16, 8)] = f2b(v);
                            else
                                Cout[(size_t)row * ldc + cbase + j * 16] = f2b(v);
                        }
                    }
            }
        }
        __syncthreads();   // protect LDS reuse across tile iterations
    }
}

// tail GEMM: R[N,512] = relu?(h@Ws[e]^T + neigh_e@Wn[e]^T + b); K=512 from
// two slab-A sources; fp32 row-major output.
__device__ __forceinline__ void dev_tail(
    const u16* __restrict__ h, const u16* __restrict__ neigh,
    const u16* __restrict__ Ws, const u16* __restrict__ Wn,
    const float* __restrict__ bias, int relu, float* __restrict__ R,
    int nid, int grid, int bid, u16 (*As)[4096], u16 (*Bs)[4096])
{
    const int tid = threadIdx.x, lane = tid & 63;
    const int w = tid >> 6, wm = w >> 2, wn = w & 3;
    for (int id = bid; id < nid; id += grid) {
        const int g = id >> 5, rem = id & 31;      // CS = 4
        const int cs = rem >> 3, bmi = (g << 3) | (rem & 7);
        if (bmi < NBANDS) {
            const int bm = bmi * 128;
            const int e = cs >> 1;
            const u16* Bself  = Ws + (size_t)e * 65536 + (cs & 1) * 32768 + (size_t)tid * 8;
            const u16* Bneigh = Wn + (size_t)e * 65536 + (cs & 1) * 32768 + (size_t)tid * 8;
            const u16* ah = h + (((size_t)bmi * 8) << 12) + (size_t)tid * 8;
            const u16* an = neigh + (((size_t)bmi * 16 + e * 8) << 12) + (size_t)tid * 8;
            const int cbase = cs * 128 + wn * 32 + (lane & 15);
            float bj0 = bias[cbase], bj1 = bias[cbase + 16];
            asm volatile("" ::: "memory");
            f32x4 acc[4][2] = {};
#define TG_STAGE(S, BUF) do { \
    const u16* as_ = ((S) < 8) ? (ah + (((size_t)(S)) << 12)) \
                               : (an + (((size_t)((S) - 8)) << 12)); \
    gload16(as_, &As[BUF][(size_t)tid * 8]); \
    const u16* bs_ = ((S) < 8) ? (Bself + (((size_t)(S)) << 12)) \
                               : (Bneigh + (((size_t)((S) - 8)) << 12)); \
    gload16(bs_, &Bs[BUF][(size_t)tid * 8]); \
} while (0)
            TG_STAGE(0, 0);
            TG_STAGE(1, 1);
#pragma unroll
            for (int s = 0; s < 16; ++s) {
                if (s + 1 < 16) asm volatile("s_waitcnt vmcnt(2)" ::: "memory");
                else            asm volatile("s_waitcnt vmcnt(0)" ::: "memory");
                __builtin_amdgcn_s_barrier();
                asm volatile("" ::: "memory");
                if (s + 2 < 16) TG_STAGE(s + 2, (s + 2) % 3);
                const int buf = s % 3;
                bf16x8 av[4], bv[2];
#pragma unroll
                for (int mi = 0; mi < 4; ++mi)
                    av[mi] = *(const bf16x8*)((const char*)As[buf] + ((wm * 4 + mi) << 10) + lane * 16);
#pragma unroll
                for (int j = 0; j < 2; ++j)
                    bv[j] = *(const bf16x8*)((const char*)Bs[buf] + ((wn * 2 + j) << 10) + lane * 16);
#pragma unroll
                for (int mi = 0; mi < 4; ++mi)
#pragma unroll
                    for (int j = 0; j < 2; ++j)
                        acc[mi][j] = __builtin_amdgcn_mfma_f32_16x16x32_bf16(av[mi], bv[j], acc[mi][j], 0, 0, 0);
            }
#undef TG_STAGE
            const int rb = bm + wm * 64 + ((lane >> 4) << 2);
#pragma unroll
            for (int j = 0; j < 2; ++j) {
                const float bj = j ? bj1 : bj0;
#pragma unroll
                for (int mi = 0; mi < 4; ++mi)
#pragma unroll
                    for (int r = 0; r < 4; ++r) {
                        const int row = rb + mi * 16 + r;
                        if (row < N_NODES) {
                            float v = acc[mi][j][r] + bj;
                            if (relu) v = fmaxf(v, 0.f);
                            R[(size_t)row * 512 + cbase + j * 16] = v;
                        }
                    }
            }
        }
        __syncthreads();
    }
}

// segment max (bf16, both etypes): one wave per (node,t); 8 waves/block.
__device__ __forceinline__ ushort4 umax4(ushort4 a, ushort4 b)
{
    a.x = a.x > b.x ? a.x : b.x;
    a.y = a.y > b.y ? a.y : b.y;
    a.z = a.z > b.z ? a.z : b.z;
    a.w = a.w > b.w ? a.w : b.w;
    return a;
}

__device__ __forceinline__ void dev_segmax(
    const u16* __restrict__ hp, const int* __restrict__ off,
    const int* __restrict__ esrc, u16* __restrict__ neigh, int grid, int bid)
{
    const int tid = threadIdx.x;
    const int lane = tid & 63;
    for (int base = bid * 8; base < 2 * N_NODES; base += grid * 8) {
        const int g = base + (tid >> 6);
        if (g < 2 * N_NODES) {
            const int t = (g >= N_NODES) ? 1 : 0;
            const int node = g - t * N_NODES;
            const int co = t * D_H + lane * 4;
            const int e0 = off[g], e1 = off[g + 1];
            ushort4 acc = make_ushort4(0, 0, 0, 0);
            int e = e0;
            for (; e + 4 <= e1; e += 4) {
                const int s0 = esrc[e + 0], s1 = esrc[e + 1];
                const int s2 = esrc[e + 2], s3 = esrc[e + 3];
                const ushort4 v0 = *(const ushort4*)(hp + (size_t)s0 * 512 + co);
                const ushort4 v1 = *(const ushort4*)(hp + (size_t)s1 * 512 + co);
                const ushort4 v2 = *(const ushort4*)(hp + (size_t)s2 * 512 + co);
                const ushort4 v3 = *(const ushort4*)(hp + (size_t)s3 * 512 + co);
                acc = umax4(umax4(umax4(acc, v0), umax4(v1, v2)), v3);
            }
            for (; e < e1; ++e)
                acc = umax4(acc, *(const ushort4*)(hp + (size_t)esrc[e] * 512 + co));
            *(ushort4*)(neigh + slab_addr(node, co, 16)) = acc;
        }
    }
}

// LN + etype-sum: one wave per row; 8 rows/block-iter.
template <int LAST>
__device__ __forceinline__ void dev_ln(
    const float* __restrict__ R, const float* __restrict__ gamma,
    const float* __restrict__ beta, void* __restrict__ outp, int grid, int bid)
{
    const int tid = threadIdx.x;
    const int lane = tid & 63;
    for (int base = bid * 8; base < N_NODES; base += grid * 8) {
        const int row = base + (tid >> 6);
        if (row < N_NODES) {
            const float4 v0 = ((const float4*)R)[(size_t)row * 128 + lane];
            const float4 v1 = ((const float4*)R)[(size_t)row * 128 + 64 + lane];
            float s0 = v0.x + v0.y + v0.z + v0.w;
            float q0 = v0.x * v0.x + v0.y * v0.y + v0.z * v0.z + v0.w * v0.w;
            float s1 = v1.x + v1.y + v1.z + v1.w;
            float q1 = v1.x * v1.x + v1.y * v1.y + v1.z * v1.z + v1.w * v1.w;
#pragma unroll
            for (int o = 1; o < 64; o <<= 1) {
                s0 += __shfl_xor(s0, o); q0 += __shfl_xor(q0, o);
                s1 += __shfl_xor(s1, o); q1 += __shfl_xor(q1, o);
            }
            const float m0 = s0 * (1.f / 256.f), m1 = s1 * (1.f / 256.f);
            const float i0 = rsqrtf(q0 * (1.f / 256.f) - m0 * m0 + 1e-5f);
            const float i1 = rsqrtf(q1 * (1.f / 256.f) - m1 * m1 + 1e-5f);
            const float4 g0 = ((const float4*)gamma)[lane];
            const float4 b0 = ((const float4*)beta)[lane];
            const float4 g1 = ((const float4*)(gamma + 256))[lane];
            const float4 b1 = ((const float4*)(beta + 256))[lane];
            const float o0 = (v0.x - m0) * i0 * g0.x + b0.x + (v1.x - m1) * i1 * g1.x + b1.x;
            const float o1 = (v0.y - m0) * i0 * g0.y + b0.y + (v1.y - m1) * i1 * g1.y + b1.y;
            const float o2 = (v0.z - m0) * i0 * g0.z + b0.z + (v1.z - m1) * i1 * g1.z + b1.z;
            const float o3 = (v0.w - m0) * i0 * g0.w + b0.w + (v1.w - m1) * i1 * g1.w + b1.w;
            if (LAST) {
                ((float4*)outp)[(size_t)row * 64 + lane] = make_float4(o0, o1, o2, o3);
            } else {
                ushort4 u;
                u.x = f2b(o0); u.y = f2b(o1); u.z = f2b(o2); u.w = f2b(o3);
                *(ushort4*)((u16*)outp + slab_addr(row, lane * 4, 8)) = u;
            }
        }
    }
}

// ================= cooperative mega-kernel =================
struct MArgs {
    const u16 *xb, *wlin, *wpool, *wself, *wneigh;
    const float *blin, *bpool, *bconv, *gamma, *beta;
    const int *off, *esrc;
    u16 *h_a, *h_b, *hp, *neigh;
    float *R;
    float *dout;
};

__global__ __launch_bounds__(512, 4) void mega_kernel(MArgs a)
{
    __shared__ __align__(16) u16 As[3][4096];
    __shared__ __align__(16) u16 Bs[3][4096];
    cg::grid_group gg = cg::this_grid();
    const int grid = gridDim.x, bid = blockIdx.x;
    const int MGRP16 = ((NBANDS + 7) / 8) * 16;   // 320
    const int MGRP32 = MGRP16 * 2;                // 640

    // h0 = bf16(xb @ Wlin^T + blin), slab out
    dev_gemm<16, 2, 1>(a.xb, a.wlin, a.blin, a.h_a, 0, 0, MGRP16, grid, bid, As, Bs);
    const u16* h = a.h_a;
    u16* hn = a.h_b;
    for (int l = 0; l < L_LAYERS; ++l) {
        const size_t wlo = (size_t)l * T_ETYPES * D_H * D_H;
        const size_t blo = (size_t)l * T_ETYPES * D_H;
        gg.sync();
        dev_gemm<8, 4, 0>(h, a.wpool + wlo, a.bpool + blo, a.hp,
                          T_ETYPES * D_H, 1, MGRP32, grid, bid, As, Bs);
        gg.sync();
        dev_segmax(a.hp, a.off, a.esrc, a.neigh, grid, bid);
        gg.sync();
        dev_tail(h, a.neigh, a.wself + wlo, a.wneigh + wlo, a.bconv + blo,
                 (l < L_LAYERS - 1) ? 1 : 0, a.R, MGRP32, grid, bid, As, Bs);
        gg.sync();
        if (l < L_LAYERS - 1) dev_ln<0>(a.R, a.gamma + blo, a.beta + blo, hn, grid, bid);
        else                  dev_ln<1>(a.R, a.gamma + blo, a.beta + blo, a.dout, grid, bid);
        u16* t = (u16*)h; h = hn; hn = t;
    }
}

// ================= fallback discrete wrappers =================
template <int NSTEPS, int CS, int SLABOUT>
__global__ __launch_bounds__(512) void k_gemm(
    const u16* A, const u16* Wf, const float* bias, u16* C, int ldc, int relu, int nid)
{
    __shared__ __align__(16) u16 As[3][4096];
    __shared__ __align__(16) u16 Bs[3][4096];
    dev_gemm<NSTEPS, CS, SLABOUT>(A, Wf, bias, C, ldc, relu, nid, gridDim.x, blockIdx.x, As, Bs);
}

__global__ __launch_bounds__(512) void k_tail(
    const u16* h, const u16* neigh, const u16* Ws, const u16* Wn,
    const float* bias, int relu, float* R, int nid)
{
    __shared__ __align__(16) u16 As[3][4096];
    __shared__ __align__(16) u16 Bs[3][4096];
    dev_tail(h, neigh, Ws, Wn, bias, relu, R, nid, gridDim.x, blockIdx.x, As, Bs);
}

__global__ __launch_bounds__(512) void k_segmax(
    const u16* hp, const int* off, const int* esrc, u16* neigh)
{
    dev_segmax(hp, off, esrc, neigh, gridDim.x, blockIdx.x);
}

template <int LAST>
__global__ __launch_bounds__(512) void k_ln(
    const float* R, const float* gamma, const float* beta, void* outp)
{
    dev_ln<LAST>(R, gamma, beta, outp, gridDim.x, blockIdx.x);
}

// ---------------- CSR build (both etypes batched; once per launch) ----------------
__global__ __launch_bounds__(256) void count_deg_kernel(
    const int* __restrict__ dst, int* __restrict__ cnt, int E2)
{
    int e = blockIdx.x * 256 + threadIdx.x;
    if (e < E2) {
        const int base = (e >= E_EDGES) ? N_NODES : 0;
        atomicAdd(&cnt[base + dst[e]], 1);
    }
}

__global__ __launch_bounds__(256) void scanA_kernel(
    const int* __restrict__ cnt, int* __restrict__ incl, int* __restrict__ bsum, int n)
{
    __shared__ int tmp[256];
    const int tid = threadIdx.x;
    const int i = blockIdx.x * 256 + tid;
    const int v = (i < n) ? cnt[i] : 0;
    tmp[tid] = v;
    __syncthreads();
#pragma unroll
    for (int o = 1; o < 256; o <<= 1) {
        const int t = (tid >= o) ? tmp[tid - o] : 0;
        __syncthreads();
        tmp[tid] += t;
        __syncthreads();
    }
    if (i < n) incl[i] = tmp[tid];
    if (tid == 255) bsum[blockIdx.x] = tmp[255];
}

__global__ __launch_bounds__(256) void scanB_kernel(int* __restrict__ bsum, int nb)
{
    __shared__ int tmp[256];
    const int tid = threadIdx.x;
    const int v = (tid < nb) ? bsum[tid] : 0;
    tmp[tid] = v;
    __syncthreads();
#pragma unroll
    for (int o = 1; o < 256; o <<= 1) {
        const int t = (tid >= o) ? tmp[tid - o] : 0;
        __syncthreads();
        tmp[tid] += t;
        __syncthreads();
    }
    if (tid < nb) bsum[tid] = tmp[tid] - v;  // exclusive
}

__global__ __launch_bounds__(256) void scanC_kernel(
    const int* __restrict__ cnt, const int* __restrict__ incl,
    const int* __restrict__ bsum, int* __restrict__ off, int* __restrict__ cursor, int n)
{
    const int i = blockIdx.x * 256 + threadIdx.x;
    if (i < n) {
        const int e = incl[i] + bsum[blockIdx.x];
        off[i + 1] = e;
        cursor[i] = e - cnt[i];
    }
    if (i == 0) off[0] = 0;
}

__global__ __launch_bounds__(256) void fill_csr_kernel(
    const int* __restrict__ src, const int* __restrict__ dst,
    int* __restrict__ cursor, int* __restrict__ esrc, int E2)
{
    int e = blockIdx.x * 256 + threadIdx.x;
    if (e < E2) {
        const int base = (e >= E_EDGES) ? N_NODES : 0;
        const int pos = atomicAdd(&cursor[base + dst[e]], 1);
        esrc[pos] = src[e];
    }
}

extern "C" void kernel_launch(void* const* d_in, const int* in_sizes, int n_in,
                              void* d_out, int out_size, void* d_ws, size_t ws_size,
                              hipStream_t stream)
{
    const float* x      = (const float*)d_in[0];
    const int*   src    = (const int*)d_in[1];
    const int*   dst    = (const int*)d_in[2];
    const float* Wlin   = (const float*)d_in[3];
    const float* blin   = (const float*)d_in[4];
    const float* Wpool  = (const float*)d_in[5];
    const float* bpool  = (const float*)d_in[6];
    const float* Wself  = (const float*)d_in[7];
    const float* Wneigh = (const float*)d_in[8];
    const float* bconv  = (const float*)d_in[9];
    const float* gamma  = (const float*)d_in[10];
    const float* beta   = (const float*)d_in[11];

    char* p = (char*)d_ws;
    u16* hp_b    = (u16*)p; p += (size_t)N_NODES * 512 * 2;   // row-major
    u16* neigh_b = (u16*)p; p += (size_t)M_PAD * 512 * 2;     // slab
    u16* h_a     = (u16*)p; p += (size_t)M_PAD * 256 * 2;     // slab
    u16* h_b     = (u16*)p; p += (size_t)M_PAD * 256 * 2;     // slab
    u16* xb      = (u16*)p; p += (size_t)M_PAD * F_IN * 2;    // slab
    float* Rbuf  = (float*)p; p += (size_t)N_NODES * 512 * 4; // row-major
    u16* wlin_f  = (u16*)p; p += (size_t)D_H * F_IN * 2;
    const size_t WSZ = (size_t)L_LAYERS * T_ETYPES * D_H * D_H;  // 393216
    u16* wpool_f = (u16*)p; p += WSZ * 2;
    u16* wself_f = (u16*)p; p += WSZ * 2;
    u16* wneigh_f= (u16*)p; p += WSZ * 2;
    int* ip = (int*)p;
    const int NT = T_ETYPES * N_NODES;  // 40000
    int* cnt    = ip; ip += NT;
    int* incl   = ip; ip += NT;
    int* off    = ip; ip += NT + 1;
    int* cursor = ip; ip += NT;
    int* esrc   = ip; ip += T_ETYPES * E_EDGES;
    int* bsum   = ip; ip += 256;

    const dim3 blk(256);
    const int E2 = T_ETYPES * E_EDGES;
    const dim3 e2grid((E2 + 255) / 256);
    const int nScanBlk = (NT + 255) / 256;  // 157

    // ---- prep: x->slab bf16 + all weights -> fragment-slab bf16, one dispatch ----
    {
        const int nx8  = M_PAD * F_IN / 8;          // 1,286,144
        const int nl8  = D_H * F_IN / 8;            // 16384
        const int nw8  = (int)(WSZ / 8);            // 49152
        const int tot  = nx8 + nl8 + 3 * nw8;
        prep_kernel<<<dim3((tot + 255) / 256), blk, 0, stream>>>(
            x, xb, nx8,
            Wlin, wlin_f, D_H, F_IN, nl8,
            Wpool, wpool_f, T_ETYPES * D_H, D_H, nw8,
            Wself, wself_f, D_H, D_H, nw8,
            Wneigh, wneigh_f, D_H, D_H, nw8);
    }

    // ---- CSR build, both etypes batched (3-dispatch parallel scan) ----
    hipMemsetAsync(cnt, 0, (size_t)NT * sizeof(int), stream);
    count_deg_kernel<<<e2grid, blk, 0, stream>>>(dst, cnt, E2);
    scanA_kernel<<<dim3(nScanBlk), blk, 0, stream>>>(cnt, incl, bsum, NT);
    scanB_kernel<<<dim3(1), blk, 0, stream>>>(bsum, nScanBlk);
    scanC_kernel<<<dim3(nScanBlk), blk, 0, stream>>>(cnt, incl, bsum, off, cursor, NT);
    fill_csr_kernel<<<e2grid, blk, 0, stream>>>(src, dst, cursor, esrc, E2);

    // ---- main pipeline: ONE cooperative mega-kernel (h0 + 3 layers) ----
    MArgs ma;
    ma.xb = xb; ma.wlin = wlin_f; ma.wpool = wpool_f;
    ma.wself = wself_f; ma.wneigh = wneigh_f;
    ma.blin = blin; ma.bpool = bpool; ma.bconv = bconv;
    ma.gamma = gamma; ma.beta = beta;
    ma.off = off; ma.esrc = esrc;
    ma.h_a = h_a; ma.h_b = h_b; ma.hp = hp_b; ma.neigh = neigh_b;
    ma.R = Rbuf; ma.dout = (float*)d_out;

    static bool coop_dead = false;
    bool done = false;
    if (!coop_dead) {
        void* kp[] = { (void*)&ma };
        // __launch_bounds__(512,4) guarantees >=2 blocks/CU residency -> grid 512 fits.
        hipError_t e = hipLaunchCooperativeKernel(
            reinterpret_cast<const void*>(&mega_kernel),
            dim3(512), dim3(512), kp, 0, stream);
        if (e == hipSuccess) done = true;
        else coop_dead = true;
    }
    if (!done) {
        // fallback: discrete dispatches (same device code)
        const int MGRP16 = ((NBANDS + 7) / 8) * 16, MGRP32 = MGRP16 * 2;
        const dim3 blk512(512);
        k_gemm<16, 2, 1><<<dim3(MGRP16), blk512, 0, stream>>>(
            xb, wlin_f, blin, h_a, 0, 0, MGRP16);
        u16* h = h_a; u16* hn = h_b;
        for (int l = 0; l < L_LAYERS; ++l) {
            const size_t wlo = (size_t)l * T_ETYPES * D_H * D_H;
            const size_t blo = (size_t)l * T_ETYPES * D_H;
            k_gemm<8, 4, 0><<<dim3(MGRP32), blk512, 0, stream>>>(
                h, wpool_f + wlo, bpool + blo, hp_b, T_ETYPES * D_H, 1, MGRP32);
            k_segmax<<<dim3(2 * N_NODES / 8), blk512, 0, stream>>>(hp_b, off, esrc, neigh_b);
            k_tail<<<dim3(MGRP32), blk512, 0, stream>>>(
                h, neigh_b, wself_f + wlo, wneigh_f + wlo, bconv + blo,
                (l < L_LAYERS - 1) ? 1 : 0, Rbuf, MGRP32);
            if (l < L_LAYERS - 1)
                k_ln<0><<<dim3(N_NODES / 8), blk512, 0, stream>>>(Rbuf, gamma + blo, beta + blo, hn);
            else
                k_ln<1><<<dim3(N_NODES / 8), blk512, 0, stream>>>(Rbuf, gamma + blo, beta + blo, d_out);
            u16* t = h; h = hn; hn = t;
        }
    }
}

// Round 9
// 386.052 us; speedup vs baseline: 1.0197x; 1.0197x over previous
//
#include <hip/hip_runtime.h>

// Problem constants (from reference)
#define N_NODES 20000
#define F_IN    512
#define D_H     256
#define E_EDGES 200000
#define L_LAYERS 3
#define T_ETYPES 2
#define NBANDS  157   // ceil(20000/128)
#define M_PAD   (NBANDS * 128)   // 20096

typedef __attribute__((ext_vector_type(8))) short bf16x8;
typedef __attribute__((ext_vector_type(4))) float f32x4;

__device__ __forceinline__ unsigned short f2b(float f) {
    unsigned int u = __float_as_uint(f);
    u = (u + 0x7FFFu + ((u >> 16) & 1u)) >> 16;   // round-nearest-even
    return (unsigned short)u;
}
__device__ __forceinline__ unsigned int pack2(float a, float b) {
    return (unsigned int)f2b(a) | ((unsigned int)f2b(b) << 16);
}

// async global->LDS, 16B per lane; LDS dest = wave-uniform base + lane*16.
__device__ __forceinline__ void gload16(const unsigned short* g, unsigned short* l)
{
    __builtin_amdgcn_global_load_lds(
        (const __attribute__((address_space(1))) void*)g,
        (__attribute__((address_space(3))) void*)l, 16, 0, 0);
}

// Fragment-slab layout (shared by weights B-side and activations A-side):
// matrix [R, K] -> band (r>>7) x kslab (k>>5), each slab 4096 elems (8KB);
// inside: elem (r_local, kk) at ((r_local>>4)&7)<<9 | ((kk>>3)&3)<<7
//        | (r_local&15)<<3 | (kk&7).
__device__ __forceinline__ size_t slab_addr(int row, int col, int kslabs)
{
    return ((size_t)(row >> 7) * kslabs + (col >> 5)) * 4096
         + (((row >> 4) & 7) << 9) + (((col >> 3) & 3) << 7)
         + ((row & 15) << 3) + (col & 7);
}

// ---------------- prep: fp32 row-major [Mreal,K] -> bf16 slab order + count_deg ----
__device__ __forceinline__ void shufg8(const float* __restrict__ s,
                                       unsigned short* __restrict__ d,
                                       int NO, int Mreal, int K, int o8)
{
    const int matsz8 = (NO * K) >> 3;
    const int mat = o8 / matsz8;
    const int rem = o8 - mat * matsz8;
    const int dst = rem << 3;
    const int slab = dst >> 12;
    const int w = dst & 4095;
    const int spr = K >> 5;                    // kslabs per band
    const int slab_n = slab / spr, slab_k = slab - slab_n * spr;
    int row = slab_n * 128 + (((w >> 9) & 7) << 4) + ((w >> 3) & 15);
    if (row >= Mreal) row = Mreal - 1;
    const int kk = ((w >> 7) & 3) << 3;
    const size_t soff = (size_t)mat * Mreal * K + (size_t)row * K + slab_k * 32 + kk;
    const float4 a = *(const float4*)(s + soff);
    const float4 b = *(const float4*)(s + soff + 4);
    uint4 u;
    u.x = pack2(a.x, a.y); u.y = pack2(a.z, a.w);
    u.z = pack2(b.x, b.y); u.w = pack2(b.z, b.w);
    *(uint4*)(d + (size_t)mat * NO * K + dst) = u;
}

// Fused: x->slab, 4 weight shuffles, AND edge-degree count (cnt pre-zeroed).
__global__ __launch_bounds__(256) void prep_kernel(
    const float* __restrict__ x,  unsigned short* __restrict__ xb, int nx8,
    const float* __restrict__ s0, unsigned short* __restrict__ d0, int NO0, int K0, int n08,
    const float* __restrict__ s1, unsigned short* __restrict__ d1, int NO1, int K1, int n18,
    const float* __restrict__ s2, unsigned short* __restrict__ d2, int NO2, int K2, int n28,
    const float* __restrict__ s3, unsigned short* __restrict__ d3, int NO3, int K3, int n38,
    const int* __restrict__ dst, int* __restrict__ cnt, int E2)
{
    int i = blockIdx.x * 256 + threadIdx.x;
    if (i < nx8) { shufg8(x, xb, M_PAD, N_NODES, F_IN, i); return; }
    i -= nx8;
    if (i < n08) { shufg8(s0, d0, NO0, NO0, K0, i); return; }
    if ((i -= n08) < n18) { shufg8(s1, d1, NO1, NO1, K1, i); return; }
    if ((i -= n18) < n28) { shufg8(s2, d2, NO2, NO2, K2, i); return; }
    if ((i -= n28) < n38) { shufg8(s3, d3, NO3, NO3, K3, i); return; }
    if ((i -= n38) < E2) {
        const int base = (i >= E_EDGES) ? N_NODES : 0;
        atomicAdd(&cnt[base + dst[i]], 1);
    }
}

// ---------------- GEMM: 512-thr, slab-A + slab-B, counted-vmcnt, XCD swizzle -------
// C[M, cs*128 : +128] = act(A @ W^T + bias). Block 128x128, 8 waves 2x4, wave 64x32.
// A is in slab order: stage(S) = A + (bmi*NSTEPS + S)*4096 + tid*8 (contiguous 8KB).
// SLABOUT=1: C written in slab order (K=256 activations); else row-major bf16.
template <int NSTEPS, int CS, int SLABOUT>
__global__ __launch_bounds__(512) void gemm_lds(
    const unsigned short* __restrict__ A,   // slab-A, band stride NSTEPS*4096
    const unsigned short* __restrict__ Wf,  // fragment-slab weights, col-slab = cs
    const float* __restrict__ bias, unsigned short* __restrict__ Cout,
    int M, int ldc, int relu)
{
    __shared__ __align__(16) unsigned short As[3][4096];  // 8KB per buf
    __shared__ __align__(16) unsigned short Bs[3][4096];
    const int tid = threadIdx.x, lane = tid & 63;
    const int w = tid >> 6, wm = w >> 2, wn = w & 3;
    // swizzle decode: id = g*(8*CS) + cs*8 + bm8 => XCD(id%8)=bm8 shared by all cs
    const int id = blockIdx.x;
    const int g = id / (8 * CS), rem = id - g * (8 * CS);
    const int cs = rem >> 3, bmi = (g << 3) | (rem & 7);
    const int MB = (M + 127) >> 7;
    if (bmi >= MB) return;
    const int bm = bmi * 128;
    const unsigned short* slab0 = Wf + (((size_t)cs * NSTEPS) << 12);
    const unsigned short* abase = A + (((size_t)bmi * NSTEPS) << 12) + (size_t)tid * 8;
    const unsigned short* bsrc = slab0 + (size_t)tid * 8;

    // preload bias (issued before staging; retired by the first counted wait)
    const int cbase = cs * 128 + wn * 32 + (lane & 15);
    float bj[2];
#pragma unroll
    for (int j = 0; j < 2; ++j) bj[j] = bias[cbase + j * 16];
    asm volatile("" ::: "memory");

    f32x4 acc[4][2] = {};

#define GL_STAGE(S, BUF) do { \
    gload16(abase + (((size_t)(S)) << 12), &As[BUF][(size_t)tid * 8]); \
    gload16(bsrc + (((size_t)(S)) << 12), &Bs[BUF][(size_t)tid * 8]); \
} while (0)

    GL_STAGE(0, 0);
    GL_STAGE(1, 1);
#pragma unroll
    for (int s = 0; s < NSTEPS; ++s) {
        if (s + 1 < NSTEPS) asm volatile("s_waitcnt vmcnt(2)" ::: "memory");
        else                asm volatile("s_waitcnt vmcnt(0)" ::: "memory");
        __builtin_amdgcn_s_barrier();
        asm volatile("" ::: "memory");
        if (s + 2 < NSTEPS) GL_STAGE(s + 2, (s + 2) % 3);
        const int buf = s % 3;
        bf16x8 a[4], b[2];
#pragma unroll
        for (int mi = 0; mi < 4; ++mi)
            a[mi] = *(const bf16x8*)((const char*)As[buf] + ((wm * 4 + mi) << 10) + lane * 16);
#pragma unroll
        for (int j = 0; j < 2; ++j)
            b[j] = *(const bf16x8*)((const char*)Bs[buf] + ((wn * 2 + j) << 10) + lane * 16);
#pragma unroll
        for (int mi = 0; mi < 4; ++mi)
#pragma unroll
            for (int j = 0; j < 2; ++j)
                acc[mi][j] = __builtin_amdgcn_mfma_f32_16x16x32_bf16(a[mi], b[j], acc[mi][j], 0, 0, 0);
    }
#undef GL_STAGE

    // C/D layout: col = lane&15, row = (lane>>4)*4 + reg
    const int rb = bm + wm * 64 + ((lane >> 4) << 2);
#pragma unroll
    for (int j = 0; j < 2; ++j) {
#pragma unroll
        for (int mi = 0; mi < 4; ++mi)
#pragma unroll
            for (int r = 0; r < 4; ++r) {
                const int row = rb + mi * 16 + r;
                if (row < M) {
                    float v = acc[mi][j][r] + bj[j];
                    if (relu) v = fmaxf(v, 0.f);
                    if (SLABOUT)
                        Cout[slab_addr(row, cbase + j * 16, 8)] = f2b(v);
                    else
                        Cout[(size_t)row * ldc + cbase + j * 16] = f2b(v);
                }
            }
    }
}

// ---------------- tail GEMM: R[N,512] = relu?(h@Ws[e]^T + neigh_e@Wn[e]^T + b) ------
template <int RELU>
__global__ __launch_bounds__(512) void tail_gemm(
    const unsigned short* __restrict__ h,      // slab-A, K=256 (8 kslabs/band)
    const unsigned short* __restrict__ neigh,  // slab-A, K=512 (16 kslabs/band)
    const unsigned short* __restrict__ Ws,     // wself_f layer base (t0; t1 at +65536)
    const unsigned short* __restrict__ Wn,     // wneigh_f layer base
    const float* __restrict__ bias,            // [512] layer base
    float* __restrict__ R)                     // [N,512] fp32
{
    __shared__ __align__(16) unsigned short As[3][4096];
    __shared__ __align__(16) unsigned short Bs[3][4096];
    const int tid = threadIdx.x, lane = tid & 63;
    const int w = tid >> 6, wm = w >> 2, wn = w & 3;
    const int id = blockIdx.x;
    const int g = id >> 5, rem = id & 31;      // CS = 4
    const int cs = rem >> 3, bmi = (g << 3) | (rem & 7);
    if (bmi >= NBANDS) return;
    const int bm = bmi * 128;
    const int e  = cs >> 1;
    const unsigned short* Bself  = Ws + (size_t)e * 65536 + (cs & 1) * 32768;
    const unsigned short* Bneigh = Wn + (size_t)e * 65536 + (cs & 1) * 32768;
    const unsigned short* ah = h + (((size_t)bmi * 8) << 12) + (size_t)tid * 8;
    const unsigned short* an = neigh + (((size_t)bmi * 16 + e * 8) << 12) + (size_t)tid * 8;

    const int cbase = cs * 128 + wn * 32 + (lane & 15);
    float bj[2];
#pragma unroll
    for (int j = 0; j < 2; ++j) bj[j] = bias[cbase + j * 16];
    asm volatile("" ::: "memory");

    f32x4 acc[4][2] = {};

#define TG_STAGE(S, BUF) do { \
    const unsigned short* as_ = ((S) < 8) ? (ah + (((size_t)(S)) << 12)) \
                                          : (an + (((size_t)((S) - 8)) << 12)); \
    gload16(as_, &As[BUF][(size_t)tid * 8]); \
    const unsigned short* bs_ = (((S) < 8) ? (Bself + ((S) << 12)) \
                                           : (Bneigh + (((S) - 8) << 12))) \
                                + (size_t)tid * 8; \
    gload16(bs_, &Bs[BUF][(size_t)tid * 8]); \
} while (0)

    TG_STAGE(0, 0);
    TG_STAGE(1, 1);
#pragma unroll
    for (int s = 0; s < 16; ++s) {
        if (s + 1 < 16) asm volatile("s_waitcnt vmcnt(2)" ::: "memory");
        else            asm volatile("s_waitcnt vmcnt(0)" ::: "memory");
        __builtin_amdgcn_s_barrier();
        asm volatile("" ::: "memory");
        if (s + 2 < 16) TG_STAGE(s + 2, (s + 2) % 3);
        const int buf = s % 3;
        bf16x8 a[4], b[2];
#pragma unroll
        for (int mi = 0; mi < 4; ++mi)
            a[mi] = *(const bf16x8*)((const char*)As[buf] + ((wm * 4 + mi) << 10) + lane * 16);
#pragma unroll
        for (int j = 0; j < 2; ++j)
            b[j] = *(const bf16x8*)((const char*)Bs[buf] + ((wn * 2 + j) << 10) + lane * 16);
#pragma unroll
        for (int mi = 0; mi < 4; ++mi)
#pragma unroll
            for (int j = 0; j < 2; ++j)
                acc[mi][j] = __builtin_amdgcn_mfma_f32_16x16x32_bf16(a[mi], b[j], acc[mi][j], 0, 0, 0);
    }
#undef TG_STAGE

    const int rb = bm + wm * 64 + ((lane >> 4) << 2);
#pragma unroll
    for (int j = 0; j < 2; ++j) {
#pragma unroll
        for (int mi = 0; mi < 4; ++mi)
#pragma unroll
            for (int r = 0; r < 4; ++r) {
                const int row = rb + mi * 16 + r;
                if (row < N_NODES) {
                    float v = acc[mi][j][r] + bj[j];
                    if (RELU) v = fmaxf(v, 0.f);
                    R[(size_t)row * 512 + cbase + j * 16] = v;
                }
            }
    }
}

// ---------------- LN + etype-sum: out[r] = LN0(R[r,0:256]) + LN1(R[r,256:512]) ------
template <int LAST>
__global__ __launch_bounds__(256) void ln_sum_kernel(
    const float* __restrict__ R,               // [N,512] fp32 (relu already applied)
    const float* __restrict__ gamma,           // [512] layer base
    const float* __restrict__ beta,
    void* __restrict__ outp)                   // slab bf16 h  |  fp32 [N,256] d_out
{
    const int row  = blockIdx.x * 4 + (threadIdx.x >> 6);
    const int lane = threadIdx.x & 63;
    const float4 v0 = ((const float4*)R)[(size_t)row * 128 + lane];
    const float4 v1 = ((const float4*)R)[(size_t)row * 128 + 64 + lane];
    float s0 = v0.x + v0.y + v0.z + v0.w;
    float q0 = v0.x * v0.x + v0.y * v0.y + v0.z * v0.z + v0.w * v0.w;
    float s1 = v1.x + v1.y + v1.z + v1.w;
    float q1 = v1.x * v1.x + v1.y * v1.y + v1.z * v1.z + v1.w * v1.w;
#pragma unroll
    for (int o = 1; o < 64; o <<= 1) {
        s0 += __shfl_xor(s0, o); q0 += __shfl_xor(q0, o);
        s1 += __shfl_xor(s1, o); q1 += __shfl_xor(q1, o);
    }
    const float m0 = s0 * (1.f / 256.f), m1 = s1 * (1.f / 256.f);
    const float i0 = rsqrtf(q0 * (1.f / 256.f) - m0 * m0 + 1e-5f);
    const float i1 = rsqrtf(q1 * (1.f / 256.f) - m1 * m1 + 1e-5f);
    const float4 g0 = ((const float4*)gamma)[lane];
    const float4 b0 = ((const float4*)beta)[lane];
    const float4 g1 = ((const float4*)(gamma + 256))[lane];
    const float4 b1 = ((const float4*)(beta + 256))[lane];
    const float o0 = (v0.x - m0) * i0 * g0.x + b0.x + (v1.x - m1) * i1 * g1.x + b1.x;
    const float o1 = (v0.y - m0) * i0 * g0.y + b0.y + (v1.y - m1) * i1 * g1.y + b1.y;
    const float o2 = (v0.z - m0) * i0 * g0.z + b0.z + (v1.z - m1) * i1 * g1.z + b1.z;
    const float o3 = (v0.w - m0) * i0 * g0.w + b0.w + (v1.w - m1) * i1 * g1.w + b1.w;
    if (LAST) {
        ((float4*)outp)[(size_t)row * 64 + lane] = make_float4(o0, o1, o2, o3);
    } else {
        ushort4 u;
        u.x = f2b(o0); u.y = f2b(o1); u.z = f2b(o2); u.w = f2b(o3);
        *(ushort4*)((unsigned short*)outp + slab_addr(row, lane * 4, 8)) = u;
    }
}

// ---------------- CSR build: scanA + scanC (scanB folded into scanC) ----------------
__global__ __launch_bounds__(256) void scanA_kernel(
    const int* __restrict__ cnt, int* __restrict__ incl, int* __restrict__ bsum, int n)
{
    __shared__ int tmp[256];
    const int tid = threadIdx.x;
    const int i = blockIdx.x * 256 + tid;
    const int v = (i < n) ? cnt[i] : 0;
    tmp[tid] = v;
    __syncthreads();
#pragma unroll
    for (int o = 1; o < 256; o <<= 1) {
        const int t = (tid >= o) ? tmp[tid - o] : 0;
        __syncthreads();
        tmp[tid] += t;
        __syncthreads();
    }
    if (i < n) incl[i] = tmp[tid];
    if (tid == 255) bsum[blockIdx.x] = tmp[255];
}

// Each block reduces its bsum prefix in-block (157 values), then emits off/cursor.
__global__ __launch_bounds__(256) void scanC_kernel(
    const int* __restrict__ cnt, const int* __restrict__ incl,
    const int* __restrict__ bsum, int* __restrict__ off, int* __restrict__ cursor,
    int n, int nb)
{
    __shared__ int red[256];
    const int tid = threadIdx.x;
    red[tid] = (tid < blockIdx.x && tid < nb) ? bsum[tid] : 0;
    __syncthreads();
#pragma unroll
    for (int o = 128; o > 0; o >>= 1) {
        if (tid < o) red[tid] += red[tid + o];
        __syncthreads();
    }
    const int base = red[0];
    const int i = blockIdx.x * 256 + tid;
    if (i < n) {
        const int e = incl[i] + base;
        off[i + 1] = e;
        cursor[i] = e - cnt[i];
    }
    if (i == 0) off[0] = 0;
}

__global__ __launch_bounds__(256) void fill_csr_kernel(
    const int* __restrict__ src, const int* __restrict__ dst,
    int* __restrict__ cursor, int* __restrict__ esrc, int E2)
{
    int e = blockIdx.x * 256 + threadIdx.x;
    if (e < E2) {
        const int base = (e >= E_EDGES) ? N_NODES : 0;
        const int pos = atomicAdd(&cursor[base + dst[e]], 1);
        esrc[pos] = src[e];
    }
}

// ---------------- segment max: one wave per (node,t), 8-deep gather pipeline -------
__device__ __forceinline__ ushort4 umax4(ushort4 a, ushort4 b)
{
    a.x = a.x > b.x ? a.x : b.x;
    a.y = a.y > b.y ? a.y : b.y;
    a.z = a.z > b.z ? a.z : b.z;
    a.w = a.w > b.w ? a.w : b.w;
    return a;
}

__global__ __launch_bounds__(256) void seg_max_kernel(
    const unsigned short* __restrict__ hp, const int* __restrict__ off,
    const int* __restrict__ esrc, unsigned short* __restrict__ neigh)
{
    const int g = blockIdx.x * 4 + (threadIdx.x >> 6);
    if (g >= 2 * N_NODES) return;
    const int t = (g >= N_NODES) ? 1 : 0;
    const int node = g - t * N_NODES;
    const int lane = threadIdx.x & 63;
    const int co = t * D_H + lane * 4;
    const int e0 = off[g], e1 = off[g + 1];
    ushort4 acc0 = make_ushort4(0, 0, 0, 0);
    ushort4 acc1 = make_ushort4(0, 0, 0, 0);
    int e = e0;
    for (; e + 8 <= e1; e += 8) {
        const int s0 = esrc[e + 0], s1 = esrc[e + 1];
        const int s2 = esrc[e + 2], s3 = esrc[e + 3];
        const int s4 = esrc[e + 4], s5 = esrc[e + 5];
        const int s6 = esrc[e + 6], s7 = esrc[e + 7];
        const ushort4 v0 = *(const ushort4*)(hp + (size_t)s0 * 512 + co);
        const ushort4 v1 = *(const ushort4*)(hp + (size_t)s1 * 512 + co);
        const ushort4 v2 = *(const ushort4*)(hp + (size_t)s2 * 512 + co);
        const ushort4 v3 = *(const ushort4*)(hp + (size_t)s3 * 512 + co);
        const ushort4 v4 = *(const ushort4*)(hp + (size_t)s4 * 512 + co);
        const ushort4 v5 = *(const ushort4*)(hp + (size_t)s5 * 512 + co);
        const ushort4 v6 = *(const ushort4*)(hp + (size_t)s6 * 512 + co);
        const ushort4 v7 = *(const ushort4*)(hp + (size_t)s7 * 512 + co);
        acc0 = umax4(acc0, umax4(umax4(v0, v1), umax4(v2, v3)));
        acc1 = umax4(acc1, umax4(umax4(v4, v5), umax4(v6, v7)));
    }
    for (; e < e1; ++e)
        acc0 = umax4(acc0, *(const ushort4*)(hp + (size_t)esrc[e] * 512 + co));
    const ushort4 acc = umax4(acc0, acc1);
    // slab write: neigh is A-input of tail (K=512 -> 16 kslabs/band)
    *(ushort4*)(neigh + slab_addr(node, co, 16)) = acc;
}

extern "C" void kernel_launch(void* const* d_in, const int* in_sizes, int n_in,
                              void* d_out, int out_size, void* d_ws, size_t ws_size,
                              hipStream_t stream)
{
    const float* x      = (const float*)d_in[0];
    const int*   src    = (const int*)d_in[1];
    const int*   dst    = (const int*)d_in[2];
    const float* Wlin   = (const float*)d_in[3];
    const float* blin   = (const float*)d_in[4];
    const float* Wpool  = (const float*)d_in[5];
    const float* bpool  = (const float*)d_in[6];
    const float* Wself  = (const float*)d_in[7];
    const float* Wneigh = (const float*)d_in[8];
    const float* bconv  = (const float*)d_in[9];
    const float* gamma  = (const float*)d_in[10];
    const float* beta   = (const float*)d_in[11];

    char* p = (char*)d_ws;
    unsigned short* hp_b    = (unsigned short*)p; p += (size_t)N_NODES * 512 * 2;   // row-major
    unsigned short* neigh_b = (unsigned short*)p; p += (size_t)M_PAD * 512 * 2;     // slab
    unsigned short* h_a     = (unsigned short*)p; p += (size_t)M_PAD * 256 * 2;     // slab
    unsigned short* h_b     = (unsigned short*)p; p += (size_t)M_PAD * 256 * 2;     // slab
    unsigned short* xb      = (unsigned short*)p; p += (size_t)M_PAD * F_IN * 2;    // slab
    float*          Rbuf    = (float*)p;          p += (size_t)N_NODES * 512 * 4;   // row-major
    unsigned short* wlin_f  = (unsigned short*)p; p += (size_t)D_H * F_IN * 2;
    const size_t WSZ = (size_t)L_LAYERS * T_ETYPES * D_H * D_H;  // 393216
    unsigned short* wpool_f = (unsigned short*)p; p += WSZ * 2;
    unsigned short* wself_f = (unsigned short*)p; p += WSZ * 2;
    unsigned short* wneigh_f= (unsigned short*)p; p += WSZ * 2;
    int* ip = (int*)p;
    const int NT = T_ETYPES * N_NODES;  // 40000
    int* cnt    = ip; ip += NT;
    int* incl   = ip; ip += NT;
    int* off    = ip; ip += NT + 1;
    int* cursor = ip; ip += NT;
    int* esrc   = ip; ip += T_ETYPES * E_EDGES;
    int* bsum   = ip; ip += 256;

    const dim3 blk(256);
    const dim3 blk512(512);
    const int E2 = T_ETYPES * E_EDGES;
    const dim3 e2grid((E2 + 255) / 256);
    const int nScanBlk = (NT + 255) / 256;  // 157

    // ---- cnt zero BEFORE prep (prep does the degree count) ----
    hipMemsetAsync(cnt, 0, (size_t)NT * sizeof(int), stream);

    // ---- prep: x->slab + weights->slab + count_deg, ONE dispatch ----
    {
        const int nx8  = M_PAD * F_IN / 8;          // 1,286,144
        const int nl8  = D_H * F_IN / 8;            // 16384
        const int nw8  = (int)(WSZ / 8);            // 49152
        const int tot  = nx8 + nl8 + 3 * nw8 + E2;
        prep_kernel<<<dim3((tot + 255) / 256), blk, 0, stream>>>(
            x, xb, nx8,
            Wlin, wlin_f, D_H, F_IN, nl8,
            Wpool, wpool_f, T_ETYPES * D_H, D_H, nw8,   // per layer: [512,256]
            Wself, wself_f, D_H, D_H, nw8,              // per (l,t): [256,256]
            Wneigh, wneigh_f, D_H, D_H, nw8,
            dst, cnt, E2);
    }

    // ---- CSR: scanA + scanC (scanB folded) + fill ----
    scanA_kernel<<<dim3(nScanBlk), blk, 0, stream>>>(cnt, incl, bsum, NT);
    scanC_kernel<<<dim3(nScanBlk), blk, 0, stream>>>(cnt, incl, bsum, off, cursor, NT, nScanBlk);
    fill_csr_kernel<<<e2grid, blk, 0, stream>>>(src, dst, cursor, esrc, E2);

    const int MGRP = (NBANDS + 7) / 8;  // 20 row-tile groups (padded)

    // ---- h0 = bf16(xb @ Wlin^T + blin), K=512, CS=2, slab out ----
    gemm_lds<16, 2, 1><<<dim3(MGRP * 16), blk512, 0, stream>>>(
        xb, wlin_f, blin, h_a, N_NODES, D_H, 0);

    unsigned short* h = h_a;
    unsigned short* hn = h_b;
    const dim3 sgrid((2 * N_NODES + 3) / 4);
    const dim3 lngrid(N_NODES / 4);             // 5000, exact
    for (int l = 0; l < L_LAYERS; ++l) {
        // hp = relu(h @ Wpool[l]^T + bpool[l]) row-major [N,512], both etypes, CS=4
        gemm_lds<8, 4, 0><<<dim3(MGRP * 32), blk512, 0, stream>>>(
            h, wpool_f + (size_t)l * T_ETYPES * D_H * D_H,
            bpool + (size_t)l * T_ETYPES * D_H, hp_b, N_NODES, T_ETYPES * D_H, 1);
        // neigh = segment_max per (node, t) -> slab
        seg_max_kernel<<<sgrid, blk, 0, stream>>>(hp_b, off, esrc, neigh_b);
        // tail GEMM -> R fp32 (relu'd, bias'd), then LN+sum
        const size_t wlo = (size_t)l * T_ETYPES * D_H * D_H;
        const size_t blo = (size_t)l * T_ETYPES * D_H;
        if (l < L_LAYERS - 1) {
            tail_gemm<1><<<dim3(MGRP * 32), blk512, 0, stream>>>(
                h, neigh_b, wself_f + wlo, wneigh_f + wlo, bconv + blo, Rbuf);
            ln_sum_kernel<0><<<lngrid, blk, 0, stream>>>(
                Rbuf, gamma + blo, beta + blo, hn);
        } else {
            tail_gemm<0><<<dim3(MGRP * 32), blk512, 0, stream>>>(
                h, neigh_b, wself_f + wlo, wneigh_f + wlo, bconv + blo, Rbuf);
            ln_sum_kernel<1><<<lngrid, blk, 0, stream>>>(
                Rbuf, gamma + blo, beta + blo, d_out);
        }
        unsigned short* tmp = h; h = hn; hn = tmp;
    }
}

// Round 10
// 386.025 us; speedup vs baseline: 1.0198x; 1.0001x over previous
//
#include <hip/hip_runtime.h>

// Problem constants (from reference)
#define N_NODES 20000
#define F_IN    512
#define D_H     256
#define E_EDGES 200000
#define L_LAYERS 3
#define T_ETYPES 2
#define NBANDS  157   // ceil(20000/128)
#define M_PAD   (NBANDS * 128)   // 20096

typedef __attribute__((ext_vector_type(8))) short bf16x8;
typedef __attribute__((ext_vector_type(4))) float f32x4;

__device__ __forceinline__ unsigned short f2b(float f) {
    unsigned int u = __float_as_uint(f);
    u = (u + 0x7FFFu + ((u >> 16) & 1u)) >> 16;   // round-nearest-even
    return (unsigned short)u;
}
__device__ __forceinline__ unsigned int pack2(float a, float b) {
    return (unsigned int)f2b(a) | ((unsigned int)f2b(b) << 16);
}

// async global->LDS, 16B per lane; LDS dest = wave-uniform base + lane*16.
__device__ __forceinline__ void gload16(const unsigned short* g, unsigned short* l)
{
    __builtin_amdgcn_global_load_lds(
        (const __attribute__((address_space(1))) void*)g,
        (__attribute__((address_space(3))) void*)l, 16, 0, 0);
}

// Fragment-slab layout (shared by weights B-side and activations A-side):
// matrix [R, K] -> band (r>>7) x kslab (k>>5), each slab 4096 elems (8KB);
// inside: elem (r_local, kk) at ((r_local>>4)&7)<<9 | ((kk>>3)&3)<<7
//        | (r_local&15)<<3 | (kk&7).
__device__ __forceinline__ size_t slab_addr(int row, int col, int kslabs)
{
    return ((size_t)(row >> 7) * kslabs + (col >> 5)) * 4096
         + (((row >> 4) & 7) << 9) + (((col >> 3) & 3) << 7)
         + ((row & 15) << 3) + (col & 7);
}

// ---------------- prep: fp32 row-major [Mreal,K] -> bf16 slab order + count_deg ----
__device__ __forceinline__ void shufg8(const float* __restrict__ s,
                                       unsigned short* __restrict__ d,
                                       int NO, int Mreal, int K, int o8)
{
    const int matsz8 = (NO * K) >> 3;
    const int mat = o8 / matsz8;
    const int rem = o8 - mat * matsz8;
    const int dst = rem << 3;
    const int slab = dst >> 12;
    const int w = dst & 4095;
    const int spr = K >> 5;                    // kslabs per band
    const int slab_n = slab / spr, slab_k = slab - slab_n * spr;
    int row = slab_n * 128 + (((w >> 9) & 7) << 4) + ((w >> 3) & 15);
    if (row >= Mreal) row = Mreal - 1;
    const int kk = ((w >> 7) & 3) << 3;
    const size_t soff = (size_t)mat * Mreal * K + (size_t)row * K + slab_k * 32 + kk;
    const float4 a = *(const float4*)(s + soff);
    const float4 b = *(const float4*)(s + soff + 4);
    uint4 u;
    u.x = pack2(a.x, a.y); u.y = pack2(a.z, a.w);
    u.z = pack2(b.x, b.y); u.w = pack2(b.z, b.w);
    *(uint4*)(d + (size_t)mat * NO * K + dst) = u;
}

// Fused: x->slab, 4 weight shuffles, AND edge-degree count (cnt pre-zeroed).
__global__ __launch_bounds__(256) void prep_kernel(
    const float* __restrict__ x,  unsigned short* __restrict__ xb, int nx8,
    const float* __restrict__ s0, unsigned short* __restrict__ d0, int NO0, int K0, int n08,
    const float* __restrict__ s1, unsigned short* __restrict__ d1, int NO1, int K1, int n18,
    const float* __restrict__ s2, unsigned short* __restrict__ d2, int NO2, int K2, int n28,
    const float* __restrict__ s3, unsigned short* __restrict__ d3, int NO3, int K3, int n38,
    const int* __restrict__ dst, int* __restrict__ cnt, int E2)
{
    int i = blockIdx.x * 256 + threadIdx.x;
    if (i < nx8) { shufg8(x, xb, M_PAD, N_NODES, F_IN, i); return; }
    i -= nx8;
    if (i < n08) { shufg8(s0, d0, NO0, NO0, K0, i); return; }
    if ((i -= n08) < n18) { shufg8(s1, d1, NO1, NO1, K1, i); return; }
    if ((i -= n18) < n28) { shufg8(s2, d2, NO2, NO2, K2, i); return; }
    if ((i -= n28) < n38) { shufg8(s3, d3, NO3, NO3, K3, i); return; }
    if ((i -= n38) < E2) {
        const int base = (i >= E_EDGES) ? N_NODES : 0;
        atomicAdd(&cnt[base + dst[i]], 1);
    }
}

// ---------------- GEMM: 512-thr, slab-A + slab-B, counted-vmcnt, XCD swizzle -------
// C[M, cs*128 : +128] = act(A @ W^T + bias). Block 128x128, 8 waves 2x4, wave 64x32.
// __launch_bounds__(512, 6): pin 6 waves/EU = 3 blocks/CU co-resident (LDS 48KB x3
// = 144 <= 160; VGPR cap 85 > 56 used). Depth-2 prefetch needs the 3rd block's
// waves to cover per-step L3 latency.
template <int NSTEPS, int CS, int SLABOUT>
__global__ __launch_bounds__(512, 6) void gemm_lds(
    const unsigned short* __restrict__ A,   // slab-A, band stride NSTEPS*4096
    const unsigned short* __restrict__ Wf,  // fragment-slab weights, col-slab = cs
    const float* __restrict__ bias, unsigned short* __restrict__ Cout,
    int M, int ldc, int relu)
{
    __shared__ __align__(16) unsigned short As[3][4096];  // 8KB per buf
    __shared__ __align__(16) unsigned short Bs[3][4096];
    const int tid = threadIdx.x, lane = tid & 63;
    const int w = tid >> 6, wm = w >> 2, wn = w & 3;
    // swizzle decode: id = g*(8*CS) + cs*8 + bm8 => XCD(id%8)=bm8 shared by all cs
    const int id = blockIdx.x;
    const int g = id / (8 * CS), rem = id - g * (8 * CS);
    const int cs = rem >> 3, bmi = (g << 3) | (rem & 7);
    const int MB = (M + 127) >> 7;
    if (bmi >= MB) return;
    const int bm = bmi * 128;
    const unsigned short* slab0 = Wf + (((size_t)cs * NSTEPS) << 12);
    const unsigned short* abase = A + (((size_t)bmi * NSTEPS) << 12) + (size_t)tid * 8;
    const unsigned short* bsrc = slab0 + (size_t)tid * 8;

    // preload bias (issued before staging; retired by the first counted wait)
    const int cbase = cs * 128 + wn * 32 + (lane & 15);
    float bj[2];
#pragma unroll
    for (int j = 0; j < 2; ++j) bj[j] = bias[cbase + j * 16];
    asm volatile("" ::: "memory");

    f32x4 acc[4][2] = {};

#define GL_STAGE(S, BUF) do { \
    gload16(abase + (((size_t)(S)) << 12), &As[BUF][(size_t)tid * 8]); \
    gload16(bsrc + (((size_t)(S)) << 12), &Bs[BUF][(size_t)tid * 8]); \
} while (0)

    GL_STAGE(0, 0);
    GL_STAGE(1, 1);
#pragma unroll
    for (int s = 0; s < NSTEPS; ++s) {
        if (s + 1 < NSTEPS) asm volatile("s_waitcnt vmcnt(2)" ::: "memory");
        else                asm volatile("s_waitcnt vmcnt(0)" ::: "memory");
        __builtin_amdgcn_s_barrier();
        asm volatile("" ::: "memory");
        if (s + 2 < NSTEPS) GL_STAGE(s + 2, (s + 2) % 3);
        const int buf = s % 3;
        bf16x8 a[4], b[2];
#pragma unroll
        for (int mi = 0; mi < 4; ++mi)
            a[mi] = *(const bf16x8*)((const char*)As[buf] + ((wm * 4 + mi) << 10) + lane * 16);
#pragma unroll
        for (int j = 0; j < 2; ++j)
            b[j] = *(const bf16x8*)((const char*)Bs[buf] + ((wn * 2 + j) << 10) + lane * 16);
#pragma unroll
        for (int mi = 0; mi < 4; ++mi)
#pragma unroll
            for (int j = 0; j < 2; ++j)
                acc[mi][j] = __builtin_amdgcn_mfma_f32_16x16x32_bf16(a[mi], b[j], acc[mi][j], 0, 0, 0);
    }
#undef GL_STAGE

    // C/D layout: col = lane&15, row = (lane>>4)*4 + reg
    const int rb = bm + wm * 64 + ((lane >> 4) << 2);
#pragma unroll
    for (int j = 0; j < 2; ++j) {
#pragma unroll
        for (int mi = 0; mi < 4; ++mi)
#pragma unroll
            for (int r = 0; r < 4; ++r) {
                const int row = rb + mi * 16 + r;
                if (row < M) {
                    float v = acc[mi][j][r] + bj[j];
                    if (relu) v = fmaxf(v, 0.f);
                    if (SLABOUT)
                        Cout[slab_addr(row, cbase + j * 16, 8)] = f2b(v);
                    else
                        Cout[(size_t)row * ldc + cbase + j * 16] = f2b(v);
                }
            }
    }
}

// ---------------- tail GEMM: R[N,512] = relu?(h@Ws[e]^T + neigh_e@Wn[e]^T + b) ------
template <int RELU>
__global__ __launch_bounds__(512, 6) void tail_gemm(
    const unsigned short* __restrict__ h,      // slab-A, K=256 (8 kslabs/band)
    const unsigned short* __restrict__ neigh,  // slab-A, K=512 (16 kslabs/band)
    const unsigned short* __restrict__ Ws,     // wself_f layer base (t0; t1 at +65536)
    const unsigned short* __restrict__ Wn,     // wneigh_f layer base
    const float* __restrict__ bias,            // [512] layer base
    float* __restrict__ R)                     // [N,512] fp32
{
    __shared__ __align__(16) unsigned short As[3][4096];
    __shared__ __align__(16) unsigned short Bs[3][4096];
    const int tid = threadIdx.x, lane = tid & 63;
    const int w = tid >> 6, wm = w >> 2, wn = w & 3;
    const int id = blockIdx.x;
    const int g = id >> 5, rem = id & 31;      // CS = 4
    const int cs = rem >> 3, bmi = (g << 3) | (rem & 7);
    if (bmi >= NBANDS) return;
    const int bm = bmi * 128;
    const int e  = cs >> 1;
    const unsigned short* Bself  = Ws + (size_t)e * 65536 + (cs & 1) * 32768;
    const unsigned short* Bneigh = Wn + (size_t)e * 65536 + (cs & 1) * 32768;
    const unsigned short* ah = h + (((size_t)bmi * 8) << 12) + (size_t)tid * 8;
    const unsigned short* an = neigh + (((size_t)bmi * 16 + e * 8) << 12) + (size_t)tid * 8;

    const int cbase = cs * 128 + wn * 32 + (lane & 15);
    float bj[2];
#pragma unroll
    for (int j = 0; j < 2; ++j) bj[j] = bias[cbase + j * 16];
    asm volatile("" ::: "memory");

    f32x4 acc[4][2] = {};

#define TG_STAGE(S, BUF) do { \
    const unsigned short* as_ = ((S) < 8) ? (ah + (((size_t)(S)) << 12)) \
                                          : (an + (((size_t)((S) - 8)) << 12)); \
    gload16(as_, &As[BUF][(size_t)tid * 8]); \
    const unsigned short* bs_ = (((S) < 8) ? (Bself + ((S) << 12)) \
                                           : (Bneigh + (((S) - 8) << 12))) \
                                + (size_t)tid * 8; \
    gload16(bs_, &Bs[BUF][(size_t)tid * 8]); \
} while (0)

    TG_STAGE(0, 0);
    TG_STAGE(1, 1);
#pragma unroll
    for (int s = 0; s < 16; ++s) {
        if (s + 1 < 16) asm volatile("s_waitcnt vmcnt(2)" ::: "memory");
        else            asm volatile("s_waitcnt vmcnt(0)" ::: "memory");
        __builtin_amdgcn_s_barrier();
        asm volatile("" ::: "memory");
        if (s + 2 < 16) TG_STAGE(s + 2, (s + 2) % 3);
        const int buf = s % 3;
        bf16x8 a[4], b[2];
#pragma unroll
        for (int mi = 0; mi < 4; ++mi)
            a[mi] = *(const bf16x8*)((const char*)As[buf] + ((wm * 4 + mi) << 10) + lane * 16);
#pragma unroll
        for (int j = 0; j < 2; ++j)
            b[j] = *(const bf16x8*)((const char*)Bs[buf] + ((wn * 2 + j) << 10) + lane * 16);
#pragma unroll
        for (int mi = 0; mi < 4; ++mi)
#pragma unroll
            for (int j = 0; j < 2; ++j)
                acc[mi][j] = __builtin_amdgcn_mfma_f32_16x16x32_bf16(a[mi], b[j], acc[mi][j], 0, 0, 0);
    }
#undef TG_STAGE

    const int rb = bm + wm * 64 + ((lane >> 4) << 2);
#pragma unroll
    for (int j = 0; j < 2; ++j) {
#pragma unroll
        for (int mi = 0; mi < 4; ++mi)
#pragma unroll
            for (int r = 0; r < 4; ++r) {
                const int row = rb + mi * 16 + r;
                if (row < N_NODES) {
                    float v = acc[mi][j][r] + bj[j];
                    if (RELU) v = fmaxf(v, 0.f);
                    R[(size_t)row * 512 + cbase + j * 16] = v;
                }
            }
    }
}

// ---------------- LN + etype-sum: out[r] = LN0(R[r,0:256]) + LN1(R[r,256:512]) ------
// 8 waves/block, one wave per row.
template <int LAST>
__global__ __launch_bounds__(512) void ln_sum_kernel(
    const float* __restrict__ R,               // [N,512] fp32 (relu already applied)
    const float* __restrict__ gamma,           // [512] layer base
    const float* __restrict__ beta,
    void* __restrict__ outp)                   // slab bf16 h  |  fp32 [N,256] d_out
{
    const int row  = blockIdx.x * 8 + (threadIdx.x >> 6);
    if (row >= N_NODES) return;
    const int lane = threadIdx.x & 63;
    const float4 v0 = ((const float4*)R)[(size_t)row * 128 + lane];
    const float4 v1 = ((const float4*)R)[(size_t)row * 128 + 64 + lane];
    float s0 = v0.x + v0.y + v0.z + v0.w;
    float q0 = v0.x * v0.x + v0.y * v0.y + v0.z * v0.z + v0.w * v0.w;
    float s1 = v1.x + v1.y + v1.z + v1.w;
    float q1 = v1.x * v1.x + v1.y * v1.y + v1.z * v1.z + v1.w * v1.w;
#pragma unroll
    for (int o = 1; o < 64; o <<= 1) {
        s0 += __shfl_xor(s0, o); q0 += __shfl_xor(q0, o);
        s1 += __shfl_xor(s1, o); q1 += __shfl_xor(q1, o);
    }
    const float m0 = s0 * (1.f / 256.f), m1 = s1 * (1.f / 256.f);
    const float i0 = rsqrtf(q0 * (1.f / 256.f) - m0 * m0 + 1e-5f);
    const float i1 = rsqrtf(q1 * (1.f / 256.f) - m1 * m1 + 1e-5f);
    const float4 g0 = ((const float4*)gamma)[lane];
    const float4 b0 = ((const float4*)beta)[lane];
    const float4 g1 = ((const float4*)(gamma + 256))[lane];
    const float4 b1 = ((const float4*)(beta + 256))[lane];
    const float o0 = (v0.x - m0) * i0 * g0.x + b0.x + (v1.x - m1) * i1 * g1.x + b1.x;
    const float o1 = (v0.y - m0) * i0 * g0.y + b0.y + (v1.y - m1) * i1 * g1.y + b1.y;
    const float o2 = (v0.z - m0) * i0 * g0.z + b0.z + (v1.z - m1) * i1 * g1.z + b1.z;
    const float o3 = (v0.w - m0) * i0 * g0.w + b0.w + (v1.w - m1) * i1 * g1.w + b1.w;
    if (LAST) {
        ((float4*)outp)[(size_t)row * 64 + lane] = make_float4(o0, o1, o2, o3);
    } else {
        ushort4 u;
        u.x = f2b(o0); u.y = f2b(o1); u.z = f2b(o2); u.w = f2b(o3);
        *(ushort4*)((unsigned short*)outp + slab_addr(row, lane * 4, 8)) = u;
    }
}

// ---------------- CSR build: scanA + scanC (scanB folded into scanC) ----------------
__global__ __launch_bounds__(256) void scanA_kernel(
    const int* __restrict__ cnt, int* __restrict__ incl, int* __restrict__ bsum, int n)
{
    __shared__ int tmp[256];
    const int tid = threadIdx.x;
    const int i = blockIdx.x * 256 + tid;
    const int v = (i < n) ? cnt[i] : 0;
    tmp[tid] = v;
    __syncthreads();
#pragma unroll
    for (int o = 1; o < 256; o <<= 1) {
        const int t = (tid >= o) ? tmp[tid - o] : 0;
        __syncthreads();
        tmp[tid] += t;
        __syncthreads();
    }
    if (i < n) incl[i] = tmp[tid];
    if (tid == 255) bsum[blockIdx.x] = tmp[255];
}

// Each block reduces its bsum prefix in-block (157 values), then emits off/cursor.
__global__ __launch_bounds__(256) void scanC_kernel(
    const int* __restrict__ cnt, const int* __restrict__ incl,
    const int* __restrict__ bsum, int* __restrict__ off, int* __restrict__ cursor,
    int n, int nb)
{
    __shared__ int red[256];
    const int tid = threadIdx.x;
    red[tid] = (tid < blockIdx.x && tid < nb) ? bsum[tid] : 0;
    __syncthreads();
#pragma unroll
    for (int o = 128; o > 0; o >>= 1) {
        if (tid < o) red[tid] += red[tid + o];
        __syncthreads();
    }
    const int base = red[0];
    const int i = blockIdx.x * 256 + tid;
    if (i < n) {
        const int e = incl[i] + base;
        off[i + 1] = e;
        cursor[i] = e - cnt[i];
    }
    if (i == 0) off[0] = 0;
}

__global__ __launch_bounds__(256) void fill_csr_kernel(
    const int* __restrict__ src, const int* __restrict__ dst,
    int* __restrict__ cursor, int* __restrict__ esrc, int E2)
{
    int e = blockIdx.x * 256 + threadIdx.x;
    if (e < E2) {
        const int base = (e >= E_EDGES) ? N_NODES : 0;
        const int pos = atomicAdd(&cursor[base + dst[e]], 1);
        esrc[pos] = src[e];
    }
}

// ---------------- segment max: 8 waves/block, one wave per (node,t) ----------------
__device__ __forceinline__ ushort4 umax4(ushort4 a, ushort4 b)
{
    a.x = a.x > b.x ? a.x : b.x;
    a.y = a.y > b.y ? a.y : b.y;
    a.z = a.z > b.z ? a.z : b.z;
    a.w = a.w > b.w ? a.w : b.w;
    return a;
}

__global__ __launch_bounds__(512) void seg_max_kernel(
    const unsigned short* __restrict__ hp, const int* __restrict__ off,
    const int* __restrict__ esrc, unsigned short* __restrict__ neigh)
{
    const int g = blockIdx.x * 8 + (threadIdx.x >> 6);
    if (g >= 2 * N_NODES) return;
    const int t = (g >= N_NODES) ? 1 : 0;
    const int node = g - t * N_NODES;
    const int lane = threadIdx.x & 63;
    const int co = t * D_H + lane * 4;
    const int e0 = off[g], e1 = off[g + 1];
    ushort4 acc0 = make_ushort4(0, 0, 0, 0);
    ushort4 acc1 = make_ushort4(0, 0, 0, 0);
    int e = e0;
    for (; e + 8 <= e1; e += 8) {
        const int s0 = esrc[e + 0], s1 = esrc[e + 1];
        const int s2 = esrc[e + 2], s3 = esrc[e + 3];
        const int s4 = esrc[e + 4], s5 = esrc[e + 5];
        const int s6 = esrc[e + 6], s7 = esrc[e + 7];
        const ushort4 v0 = *(const ushort4*)(hp + (size_t)s0 * 512 + co);
        const ushort4 v1 = *(const ushort4*)(hp + (size_t)s1 * 512 + co);
        const ushort4 v2 = *(const ushort4*)(hp + (size_t)s2 * 512 + co);
        const ushort4 v3 = *(const ushort4*)(hp + (size_t)s3 * 512 + co);
        const ushort4 v4 = *(const ushort4*)(hp + (size_t)s4 * 512 + co);
        const ushort4 v5 = *(const ushort4*)(hp + (size_t)s5 * 512 + co);
        const ushort4 v6 = *(const ushort4*)(hp + (size_t)s6 * 512 + co);
        const ushort4 v7 = *(const ushort4*)(hp + (size_t)s7 * 512 + co);
        acc0 = umax4(acc0, umax4(umax4(v0, v1), umax4(v2, v3)));
        acc1 = umax4(acc1, umax4(umax4(v4, v5), umax4(v6, v7)));
    }
    for (; e < e1; ++e)
        acc0 = umax4(acc0, *(const ushort4*)(hp + (size_t)esrc[e] * 512 + co));
    const ushort4 acc = umax4(acc0, acc1);
    // slab write: neigh is A-input of tail (K=512 -> 16 kslabs/band)
    *(ushort4*)(neigh + slab_addr(node, co, 16)) = acc;
}

extern "C" void kernel_launch(void* const* d_in, const int* in_sizes, int n_in,
                              void* d_out, int out_size, void* d_ws, size_t ws_size,
                              hipStream_t stream)
{
    const float* x      = (const float*)d_in[0];
    const int*   src    = (const int*)d_in[1];
    const int*   dst    = (const int*)d_in[2];
    const float* Wlin   = (const float*)d_in[3];
    const float* blin   = (const float*)d_in[4];
    const float* Wpool  = (const float*)d_in[5];
    const float* bpool  = (const float*)d_in[6];
    const float* Wself  = (const float*)d_in[7];
    const float* Wneigh = (const float*)d_in[8];
    const float* bconv  = (const float*)d_in[9];
    const float* gamma  = (const float*)d_in[10];
    const float* beta   = (const float*)d_in[11];

    char* p = (char*)d_ws;
    unsigned short* hp_b    = (unsigned short*)p; p += (size_t)N_NODES * 512 * 2;   // row-major
    unsigned short* neigh_b = (unsigned short*)p; p += (size_t)M_PAD * 512 * 2;     // slab
    unsigned short* h_a     = (unsigned short*)p; p += (size_t)M_PAD * 256 * 2;     // slab
    unsigned short* h_b     = (unsigned short*)p; p += (size_t)M_PAD * 256 * 2;     // slab
    unsigned short* xb      = (unsigned short*)p; p += (size_t)M_PAD * F_IN * 2;    // slab
    float*          Rbuf    = (float*)p;          p += (size_t)N_NODES * 512 * 4;   // row-major
    unsigned short* wlin_f  = (unsigned short*)p; p += (size_t)D_H * F_IN * 2;
    const size_t WSZ = (size_t)L_LAYERS * T_ETYPES * D_H * D_H;  // 393216
    unsigned short* wpool_f = (unsigned short*)p; p += WSZ * 2;
    unsigned short* wself_f = (unsigned short*)p; p += WSZ * 2;
    unsigned short* wneigh_f= (unsigned short*)p; p += WSZ * 2;
    int* ip = (int*)p;
    const int NT = T_ETYPES * N_NODES;  // 40000
    int* cnt    = ip; ip += NT;
    int* incl   = ip; ip += NT;
    int* off    = ip; ip += NT + 1;
    int* cursor = ip; ip += NT;
    int* esrc   = ip; ip += T_ETYPES * E_EDGES;
    int* bsum   = ip; ip += 256;

    const dim3 blk(256);
    const dim3 blk512(512);
    const int E2 = T_ETYPES * E_EDGES;
    const dim3 e2grid((E2 + 255) / 256);
    const int nScanBlk = (NT + 255) / 256;  // 157

    // ---- cnt zero BEFORE prep (prep does the degree count) ----
    hipMemsetAsync(cnt, 0, (size_t)NT * sizeof(int), stream);

    // ---- prep: x->slab + weights->slab + count_deg, ONE dispatch ----
    {
        const int nx8  = M_PAD * F_IN / 8;          // 1,286,144
        const int nl8  = D_H * F_IN / 8;            // 16384
        const int nw8  = (int)(WSZ / 8);            // 49152
        const int tot  = nx8 + nl8 + 3 * nw8 + E2;
        prep_kernel<<<dim3((tot + 255) / 256), blk, 0, stream>>>(
            x, xb, nx8,
            Wlin, wlin_f, D_H, F_IN, nl8,
            Wpool, wpool_f, T_ETYPES * D_H, D_H, nw8,   // per layer: [512,256]
            Wself, wself_f, D_H, D_H, nw8,              // per (l,t): [256,256]
            Wneigh, wneigh_f, D_H, D_H, nw8,
            dst, cnt, E2);
    }

    // ---- CSR: scanA + scanC (scanB folded) + fill ----
    scanA_kernel<<<dim3(nScanBlk), blk, 0, stream>>>(cnt, incl, bsum, NT);
    scanC_kernel<<<dim3(nScanBlk), blk, 0, stream>>>(cnt, incl, bsum, off, cursor, NT, nScanBlk);
    fill_csr_kernel<<<e2grid, blk, 0, stream>>>(src, dst, cursor, esrc, E2);

    const int MGRP = (NBANDS + 7) / 8;  // 20 row-tile groups (padded)

    // ---- h0 = bf16(xb @ Wlin^T + blin), K=512, CS=2, slab out ----
    gemm_lds<16, 2, 1><<<dim3(MGRP * 16), blk512, 0, stream>>>(
        xb, wlin_f, blin, h_a, N_NODES, D_H, 0);

    unsigned short* h = h_a;
    unsigned short* hn = h_b;
    const dim3 sgrid((2 * N_NODES + 7) / 8);    // 5000
    const dim3 lngrid((N_NODES + 7) / 8);       // 2500
    for (int l = 0; l < L_LAYERS; ++l) {
        // hp = relu(h @ Wpool[l]^T + bpool[l]) row-major [N,512], both etypes, CS=4
        gemm_lds<8, 4, 0><<<dim3(MGRP * 32), blk512, 0, stream>>>(
            h, wpool_f + (size_t)l * T_ETYPES * D_H * D_H,
            bpool + (size_t)l * T_ETYPES * D_H, hp_b, N_NODES, T_ETYPES * D_H, 1);
        // neigh = segment_max per (node, t) -> slab
        seg_max_kernel<<<sgrid, blk512, 0, stream>>>(hp_b, off, esrc, neigh_b);
        // tail GEMM -> R fp32 (relu'd, bias'd), then LN+sum
        const size_t wlo = (size_t)l * T_ETYPES * D_H * D_H;
        const size_t blo = (size_t)l * T_ETYPES * D_H;
        if (l < L_LAYERS - 1) {
            tail_gemm<1><<<dim3(MGRP * 32), blk512, 0, stream>>>(
                h, neigh_b, wself_f + wlo, wneigh_f + wlo, bconv + blo, Rbuf);
            ln_sum_kernel<0><<<lngrid, blk512, 0, stream>>>(
                Rbuf, gamma + blo, beta + blo, hn);
        } else {
            tail_gemm<0><<<dim3(MGRP * 32), blk512, 0, stream>>>(
                h, neigh_b, wself_f + wlo, wneigh_f + wlo, bconv + blo, Rbuf);
            ln_sum_kernel<1><<<lngrid, blk512, 0, stream>>>(
                Rbuf, gamma + blo, beta + blo, d_out);
        }
        unsigned short* tmp = h; h = hn; hn = tmp;
    }
}

// Round 11
// 373.691 us; speedup vs baseline: 1.0534x; 1.0330x over previous
//
#include <hip/hip_runtime.h>

// Problem constants (from reference)
#define N_NODES 20000
#define F_IN    512
#define D_H     256
#define E_EDGES 200000
#define L_LAYERS 3
#define T_ETYPES 2
#define NBANDS  157   // ceil(20000/128)
#define M_PAD   (NBANDS * 128)   // 20096

typedef __attribute__((ext_vector_type(8))) short bf16x8;
typedef __attribute__((ext_vector_type(4))) float f32x4;

__device__ __forceinline__ unsigned short f2b(float f) {
    unsigned int u = __float_as_uint(f);
    u = (u + 0x7FFFu + ((u >> 16) & 1u)) >> 16;   // round-nearest-even
    return (unsigned short)u;
}
__device__ __forceinline__ float b2f(unsigned short u) {
    return __uint_as_float((unsigned int)u << 16);
}
__device__ __forceinline__ unsigned int pack2(float a, float b) {
    return (unsigned int)f2b(a) | ((unsigned int)f2b(b) << 16);
}

// async global->LDS, 16B per lane; LDS dest = wave-uniform base + lane*16.
__device__ __forceinline__ void gload16(const unsigned short* g, unsigned short* l)
{
    __builtin_amdgcn_global_load_lds(
        (const __attribute__((address_space(1))) void*)g,
        (__attribute__((address_space(3))) void*)l, 16, 0, 0);
}

// Fragment-slab layout (shared by weights B-side and activations A-side):
// matrix [R, K] -> band (r>>7) x kslab (k>>5), each slab 4096 elems (8KB);
// inside: elem (r_local, kk) at ((r_local>>4)&7)<<9 | ((kk>>3)&3)<<7
//        | (r_local&15)<<3 | (kk&7).
__device__ __forceinline__ size_t slab_addr(int row, int col, int kslabs)
{
    return ((size_t)(row >> 7) * kslabs + (col >> 5)) * 4096
         + (((row >> 4) & 7) << 9) + (((col >> 3) & 3) << 7)
         + ((row & 15) << 3) + (col & 7);
}

// ---------------- prep: fp32 row-major [Mreal,K] -> bf16 slab order + count_deg ----
__device__ __forceinline__ void shufg8(const float* __restrict__ s,
                                       unsigned short* __restrict__ d,
                                       int NO, int Mreal, int K, int o8)
{
    const int matsz8 = (NO * K) >> 3;
    const int mat = o8 / matsz8;
    const int rem = o8 - mat * matsz8;
    const int dst = rem << 3;
    const int slab = dst >> 12;
    const int w = dst & 4095;
    const int spr = K >> 5;                    // kslabs per band
    const int slab_n = slab / spr, slab_k = slab - slab_n * spr;
    int row = slab_n * 128 + (((w >> 9) & 7) << 4) + ((w >> 3) & 15);
    if (row >= Mreal) row = Mreal - 1;
    const int kk = ((w >> 7) & 3) << 3;
    const size_t soff = (size_t)mat * Mreal * K + (size_t)row * K + slab_k * 32 + kk;
    const float4 a = *(const float4*)(s + soff);
    const float4 b = *(const float4*)(s + soff + 4);
    uint4 u;
    u.x = pack2(a.x, a.y); u.y = pack2(a.z, a.w);
    u.z = pack2(b.x, b.y); u.w = pack2(b.z, b.w);
    *(uint4*)(d + (size_t)mat * NO * K + dst) = u;
}

// Fused: x->slab, 4 weight shuffles, AND edge-degree count (cnt pre-zeroed).
__global__ __launch_bounds__(256) void prep_kernel(
    const float* __restrict__ x,  unsigned short* __restrict__ xb, int nx8,
    const float* __restrict__ s0, unsigned short* __restrict__ d0, int NO0, int K0, int n08,
    const float* __restrict__ s1, unsigned short* __restrict__ d1, int NO1, int K1, int n18,
    const float* __restrict__ s2, unsigned short* __restrict__ d2, int NO2, int K2, int n28,
    const float* __restrict__ s3, unsigned short* __restrict__ d3, int NO3, int K3, int n38,
    const int* __restrict__ dst, int* __restrict__ cnt, int E2)
{
    int i = blockIdx.x * 256 + threadIdx.x;
    if (i < nx8) { shufg8(x, xb, M_PAD, N_NODES, F_IN, i); return; }
    i -= nx8;
    if (i < n08) { shufg8(s0, d0, NO0, NO0, K0, i); return; }
    if ((i -= n08) < n18) { shufg8(s1, d1, NO1, NO1, K1, i); return; }
    if ((i -= n18) < n28) { shufg8(s2, d2, NO2, NO2, K2, i); return; }
    if ((i -= n28) < n38) { shufg8(s3, d3, NO3, NO3, K3, i); return; }
    if ((i -= n38) < E2) {
        const int base = (i >= E_EDGES) ? N_NODES : 0;
        atomicAdd(&cnt[base + dst[i]], 1);
    }
}

// ---------------- GEMM: 512-thr, slab-A + slab-B, counted-vmcnt, XCD swizzle -------
// C[M, cs*128 : +128] = act(A @ W^T + bias). Block 128x128, 8 waves 2x4, wave 64x32.
template <int NSTEPS, int CS, int SLABOUT>
__global__ __launch_bounds__(512, 6) void gemm_lds(
    const unsigned short* __restrict__ A,   // slab-A, band stride NSTEPS*4096
    const unsigned short* __restrict__ Wf,  // fragment-slab weights, col-slab = cs
    const float* __restrict__ bias, unsigned short* __restrict__ Cout,
    int M, int ldc, int relu)
{
    __shared__ __align__(16) unsigned short As[3][4096];  // 8KB per buf
    __shared__ __align__(16) unsigned short Bs[3][4096];
    const int tid = threadIdx.x, lane = tid & 63;
    const int w = tid >> 6, wm = w >> 2, wn = w & 3;
    // swizzle decode: id = g*(8*CS) + cs*8 + bm8 => XCD(id%8)=bm8 shared by all cs
    const int id = blockIdx.x;
    const int g = id / (8 * CS), rem = id - g * (8 * CS);
    const int cs = rem >> 3, bmi = (g << 3) | (rem & 7);
    const int MB = (M + 127) >> 7;
    if (bmi >= MB) return;
    const int bm = bmi * 128;
    const unsigned short* slab0 = Wf + (((size_t)cs * NSTEPS) << 12);
    const unsigned short* abase = A + (((size_t)bmi * NSTEPS) << 12) + (size_t)tid * 8;
    const unsigned short* bsrc = slab0 + (size_t)tid * 8;

    // preload bias (issued before staging; retired by the first counted wait)
    const int cbase = cs * 128 + wn * 32 + (lane & 15);
    float bj[2];
#pragma unroll
    for (int j = 0; j < 2; ++j) bj[j] = bias[cbase + j * 16];
    asm volatile("" ::: "memory");

    f32x4 acc[4][2] = {};

#define GL_STAGE(S, BUF) do { \
    gload16(abase + (((size_t)(S)) << 12), &As[BUF][(size_t)tid * 8]); \
    gload16(bsrc + (((size_t)(S)) << 12), &Bs[BUF][(size_t)tid * 8]); \
} while (0)

    GL_STAGE(0, 0);
    GL_STAGE(1, 1);
#pragma unroll
    for (int s = 0; s < NSTEPS; ++s) {
        if (s + 1 < NSTEPS) asm volatile("s_waitcnt vmcnt(2)" ::: "memory");
        else                asm volatile("s_waitcnt vmcnt(0)" ::: "memory");
        __builtin_amdgcn_s_barrier();
        asm volatile("" ::: "memory");
        if (s + 2 < NSTEPS) GL_STAGE(s + 2, (s + 2) % 3);
        const int buf = s % 3;
        bf16x8 a[4], b[2];
#pragma unroll
        for (int mi = 0; mi < 4; ++mi)
            a[mi] = *(const bf16x8*)((const char*)As[buf] + ((wm * 4 + mi) << 10) + lane * 16);
#pragma unroll
        for (int j = 0; j < 2; ++j)
            b[j] = *(const bf16x8*)((const char*)Bs[buf] + ((wn * 2 + j) << 10) + lane * 16);
#pragma unroll
        for (int mi = 0; mi < 4; ++mi)
#pragma unroll
            for (int j = 0; j < 2; ++j)
                acc[mi][j] = __builtin_amdgcn_mfma_f32_16x16x32_bf16(a[mi], b[j], acc[mi][j], 0, 0, 0);
    }
#undef GL_STAGE

    // C/D layout: col = lane&15, row = (lane>>4)*4 + reg
    const int rb = bm + wm * 64 + ((lane >> 4) << 2);
#pragma unroll
    for (int j = 0; j < 2; ++j) {
#pragma unroll
        for (int mi = 0; mi < 4; ++mi)
#pragma unroll
            for (int r = 0; r < 4; ++r) {
                const int row = rb + mi * 16 + r;
                if (row < M) {
                    float v = acc[mi][j][r] + bj[j];
                    if (relu) v = fmaxf(v, 0.f);
                    if (SLABOUT)
                        Cout[slab_addr(row, cbase + j * 16, 8)] = f2b(v);
                    else
                        Cout[(size_t)row * ldc + cbase + j * 16] = f2b(v);
                }
            }
    }
}

// ---------------- tail GEMM: R[N,512](bf16) = relu?(h@Ws[e]^T + neigh_e@Wn[e]^T + b) --
template <int RELU>
__global__ __launch_bounds__(512, 6) void tail_gemm(
    const unsigned short* __restrict__ h,      // slab-A, K=256 (8 kslabs/band)
    const unsigned short* __restrict__ neigh,  // slab-A, K=512 (16 kslabs/band)
    const unsigned short* __restrict__ Ws,     // wself_f layer base (t0; t1 at +65536)
    const unsigned short* __restrict__ Wn,     // wneigh_f layer base
    const float* __restrict__ bias,            // [512] layer base
    unsigned short* __restrict__ R)            // [N,512] bf16
{
    __shared__ __align__(16) unsigned short As[3][4096];
    __shared__ __align__(16) unsigned short Bs[3][4096];
    const int tid = threadIdx.x, lane = tid & 63;
    const int w = tid >> 6, wm = w >> 2, wn = w & 3;
    const int id = blockIdx.x;
    const int g = id >> 5, rem = id & 31;      // CS = 4
    const int cs = rem >> 3, bmi = (g << 3) | (rem & 7);
    if (bmi >= NBANDS) return;
    const int bm = bmi * 128;
    const int e  = cs >> 1;
    const unsigned short* Bself  = Ws + (size_t)e * 65536 + (cs & 1) * 32768;
    const unsigned short* Bneigh = Wn + (size_t)e * 65536 + (cs & 1) * 32768;
    const unsigned short* ah = h + (((size_t)bmi * 8) << 12) + (size_t)tid * 8;
    const unsigned short* an = neigh + (((size_t)bmi * 16 + e * 8) << 12) + (size_t)tid * 8;

    const int cbase = cs * 128 + wn * 32 + (lane & 15);
    float bj[2];
#pragma unroll
    for (int j = 0; j < 2; ++j) bj[j] = bias[cbase + j * 16];
    asm volatile("" ::: "memory");

    f32x4 acc[4][2] = {};

#define TG_STAGE(S, BUF) do { \
    const unsigned short* as_ = ((S) < 8) ? (ah + (((size_t)(S)) << 12)) \
                                          : (an + (((size_t)((S) - 8)) << 12)); \
    gload16(as_, &As[BUF][(size_t)tid * 8]); \
    const unsigned short* bs_ = (((S) < 8) ? (Bself + ((S) << 12)) \
                                           : (Bneigh + (((S) - 8) << 12))) \
                                + (size_t)tid * 8; \
    gload16(bs_, &Bs[BUF][(size_t)tid * 8]); \
} while (0)

    TG_STAGE(0, 0);
    TG_STAGE(1, 1);
#pragma unroll
    for (int s = 0; s < 16; ++s) {
        if (s + 1 < 16) asm volatile("s_waitcnt vmcnt(2)" ::: "memory");
        else            asm volatile("s_waitcnt vmcnt(0)" ::: "memory");
        __builtin_amdgcn_s_barrier();
        asm volatile("" ::: "memory");
        if (s + 2 < 16) TG_STAGE(s + 2, (s + 2) % 3);
        const int buf = s % 3;
        bf16x8 a[4], b[2];
#pragma unroll
        for (int mi = 0; mi < 4; ++mi)
            a[mi] = *(const bf16x8*)((const char*)As[buf] + ((wm * 4 + mi) << 10) + lane * 16);
#pragma unroll
        for (int j = 0; j < 2; ++j)
            b[j] = *(const bf16x8*)((const char*)Bs[buf] + ((wn * 2 + j) << 10) + lane * 16);
#pragma unroll
        for (int mi = 0; mi < 4; ++mi)
#pragma unroll
            for (int j = 0; j < 2; ++j)
                acc[mi][j] = __builtin_amdgcn_mfma_f32_16x16x32_bf16(a[mi], b[j], acc[mi][j], 0, 0, 0);
    }
#undef TG_STAGE

    const int rb = bm + wm * 64 + ((lane >> 4) << 2);
#pragma unroll
    for (int j = 0; j < 2; ++j) {
#pragma unroll
        for (int mi = 0; mi < 4; ++mi)
#pragma unroll
            for (int r = 0; r < 4; ++r) {
                const int row = rb + mi * 16 + r;
                if (row < N_NODES) {
                    float v = acc[mi][j][r] + bj[j];
                    if (RELU) v = fmaxf(v, 0.f);
                    R[(size_t)row * 512 + cbase + j * 16] = f2b(v);
                }
            }
    }
}

// ---------------- LN + etype-sum: out[r] = LN0(R[r,0:256]) + LN1(R[r,256:512]) ------
// 8 waves/block, one wave per row. R is bf16 (half the read traffic of fp32).
template <int LAST>
__global__ __launch_bounds__(512) void ln_sum_kernel(
    const unsigned short* __restrict__ R,      // [N,512] bf16 (relu already applied)
    const float* __restrict__ gamma,           // [512] layer base
    const float* __restrict__ beta,
    void* __restrict__ outp)                   // slab bf16 h  |  fp32 [N,256] d_out
{
    const int row  = blockIdx.x * 8 + (threadIdx.x >> 6);
    if (row >= N_NODES) return;
    const int lane = threadIdx.x & 63;
    const ushort4 r0 = ((const ushort4*)R)[(size_t)row * 128 + lane];        // cols lane*4..+3
    const ushort4 r1 = ((const ushort4*)R)[(size_t)row * 128 + 64 + lane];   // cols 256+lane*4..
    const float a0 = b2f(r0.x), a1 = b2f(r0.y), a2 = b2f(r0.z), a3 = b2f(r0.w);
    const float c0 = b2f(r1.x), c1 = b2f(r1.y), c2 = b2f(r1.z), c3 = b2f(r1.w);
    float s0 = a0 + a1 + a2 + a3;
    float q0 = a0 * a0 + a1 * a1 + a2 * a2 + a3 * a3;
    float s1 = c0 + c1 + c2 + c3;
    float q1 = c0 * c0 + c1 * c1 + c2 * c2 + c3 * c3;
#pragma unroll
    for (int o = 1; o < 64; o <<= 1) {
        s0 += __shfl_xor(s0, o); q0 += __shfl_xor(q0, o);
        s1 += __shfl_xor(s1, o); q1 += __shfl_xor(q1, o);
    }
    const float m0 = s0 * (1.f / 256.f), m1 = s1 * (1.f / 256.f);
    const float i0 = rsqrtf(q0 * (1.f / 256.f) - m0 * m0 + 1e-5f);
    const float i1 = rsqrtf(q1 * (1.f / 256.f) - m1 * m1 + 1e-5f);
    const float4 g0 = ((const float4*)gamma)[lane];
    const float4 b0 = ((const float4*)beta)[lane];
    const float4 g1 = ((const float4*)(gamma + 256))[lane];
    const float4 b1 = ((const float4*)(beta + 256))[lane];
    const float o0 = (a0 - m0) * i0 * g0.x + b0.x + (c0 - m1) * i1 * g1.x + b1.x;
    const float o1 = (a1 - m0) * i0 * g0.y + b0.y + (c1 - m1) * i1 * g1.y + b1.y;
    const float o2 = (a2 - m0) * i0 * g0.z + b0.z + (c2 - m1) * i1 * g1.z + b1.z;
    const float o3 = (a3 - m0) * i0 * g0.w + b0.w + (c3 - m1) * i1 * g1.w + b1.w;
    if (LAST) {
        ((float4*)outp)[(size_t)row * 64 + lane] = make_float4(o0, o1, o2, o3);
    } else {
        ushort4 u;
        u.x = f2b(o0); u.y = f2b(o1); u.z = f2b(o2); u.w = f2b(o3);
        *(ushort4*)((unsigned short*)outp + slab_addr(row, lane * 4, 8)) = u;
    }
}

// ---------------- CSR build: scanA + scanC (scanB folded into scanC) ----------------
__global__ __launch_bounds__(256) void scanA_kernel(
    const int* __restrict__ cnt, int* __restrict__ incl, int* __restrict__ bsum, int n)
{
    __shared__ int tmp[256];
    const int tid = threadIdx.x;
    const int i = blockIdx.x * 256 + tid;
    const int v = (i < n) ? cnt[i] : 0;
    tmp[tid] = v;
    __syncthreads();
#pragma unroll
    for (int o = 1; o < 256; o <<= 1) {
        const int t = (tid >= o) ? tmp[tid - o] : 0;
        __syncthreads();
        tmp[tid] += t;
        __syncthreads();
    }
    if (i < n) incl[i] = tmp[tid];
    if (tid == 255) bsum[blockIdx.x] = tmp[255];
}

// Each block reduces its bsum prefix in-block (157 values), then emits off/cursor.
__global__ __launch_bounds__(256) void scanC_kernel(
    const int* __restrict__ cnt, const int* __restrict__ incl,
    const int* __restrict__ bsum, int* __restrict__ off, int* __restrict__ cursor,
    int n, int nb)
{
    __shared__ int red[256];
    const int tid = threadIdx.x;
    red[tid] = (tid < blockIdx.x && tid < nb) ? bsum[tid] : 0;
    __syncthreads();
#pragma unroll
    for (int o = 128; o > 0; o >>= 1) {
        if (tid < o) red[tid] += red[tid + o];
        __syncthreads();
    }
    const int base = red[0];
    const int i = blockIdx.x * 256 + tid;
    if (i < n) {
        const int e = incl[i] + base;
        off[i + 1] = e;
        cursor[i] = e - cnt[i];
    }
    if (i == 0) off[0] = 0;
}

__global__ __launch_bounds__(256) void fill_csr_kernel(
    const int* __restrict__ src, const int* __restrict__ dst,
    int* __restrict__ cursor, int* __restrict__ esrc, int E2)
{
    int e = blockIdx.x * 256 + threadIdx.x;
    if (e < E2) {
        const int base = (e >= E_EDGES) ? N_NODES : 0;
        const int pos = atomicAdd(&cursor[base + dst[e]], 1);
        esrc[pos] = src[e];
    }
}

// ---------------- segment max: 8 waves/block, one wave per (node,t) ----------------
__device__ __forceinline__ ushort4 umax4(ushort4 a, ushort4 b)
{
    a.x = a.x > b.x ? a.x : b.x;
    a.y = a.y > b.y ? a.y : b.y;
    a.z = a.z > b.z ? a.z : b.z;
    a.w = a.w > b.w ? a.w : b.w;
    return a;
}

__global__ __launch_bounds__(512) void seg_max_kernel(
    const unsigned short* __restrict__ hp, const int* __restrict__ off,
    const int* __restrict__ esrc, unsigned short* __restrict__ neigh)
{
    const int g = blockIdx.x * 8 + (threadIdx.x >> 6);
    if (g >= 2 * N_NODES) return;
    const int t = (g >= N_NODES) ? 1 : 0;
    const int node = g - t * N_NODES;
    const int lane = threadIdx.x & 63;
    const int co = t * D_H + lane * 4;
    const int e0 = off[g], e1 = off[g + 1];
    ushort4 acc0 = make_ushort4(0, 0, 0, 0);
    ushort4 acc1 = make_ushort4(0, 0, 0, 0);
    int e = e0;
    for (; e + 8 <= e1; e += 8) {
        const int s0 = esrc[e + 0], s1 = esrc[e + 1];
        const int s2 = esrc[e + 2], s3 = esrc[e + 3];
        const int s4 = esrc[e + 4], s5 = esrc[e + 5];
        const int s6 = esrc[e + 6], s7 = esrc[e + 7];
        const ushort4 v0 = *(const ushort4*)(hp + (size_t)s0 * 512 + co);
        const ushort4 v1 = *(const ushort4*)(hp + (size_t)s1 * 512 + co);
        const ushort4 v2 = *(const ushort4*)(hp + (size_t)s2 * 512 + co);
        const ushort4 v3 = *(const ushort4*)(hp + (size_t)s3 * 512 + co);
        const ushort4 v4 = *(const ushort4*)(hp + (size_t)s4 * 512 + co);
        const ushort4 v5 = *(const ushort4*)(hp + (size_t)s5 * 512 + co);
        const ushort4 v6 = *(const ushort4*)(hp + (size_t)s6 * 512 + co);
        const ushort4 v7 = *(const ushort4*)(hp + (size_t)s7 * 512 + co);
        acc0 = umax4(acc0, umax4(umax4(v0, v1), umax4(v2, v3)));
        acc1 = umax4(acc1, umax4(umax4(v4, v5), umax4(v6, v7)));
    }
    for (; e < e1; ++e)
        acc0 = umax4(acc0, *(const ushort4*)(hp + (size_t)esrc[e] * 512 + co));
    const ushort4 acc = umax4(acc0, acc1);
    // slab write: neigh is A-input of tail (K=512 -> 16 kslabs/band)
    *(ushort4*)(neigh + slab_addr(node, co, 16)) = acc;
}

extern "C" void kernel_launch(void* const* d_in, const int* in_sizes, int n_in,
                              void* d_out, int out_size, void* d_ws, size_t ws_size,
                              hipStream_t stream)
{
    const float* x      = (const float*)d_in[0];
    const int*   src    = (const int*)d_in[1];
    const int*   dst    = (const int*)d_in[2];
    const float* Wlin   = (const float*)d_in[3];
    const float* blin   = (const float*)d_in[4];
    const float* Wpool  = (const float*)d_in[5];
    const float* bpool  = (const float*)d_in[6];
    const float* Wself  = (const float*)d_in[7];
    const float* Wneigh = (const float*)d_in[8];
    const float* bconv  = (const float*)d_in[9];
    const float* gamma  = (const float*)d_in[10];
    const float* beta   = (const float*)d_in[11];

    char* p = (char*)d_ws;
    unsigned short* hp_b    = (unsigned short*)p; p += (size_t)N_NODES * 512 * 2;   // row-major
    unsigned short* neigh_b = (unsigned short*)p; p += (size_t)M_PAD * 512 * 2;     // slab
    unsigned short* h_a     = (unsigned short*)p; p += (size_t)M_PAD * 256 * 2;     // slab
    unsigned short* h_b     = (unsigned short*)p; p += (size_t)M_PAD * 256 * 2;     // slab
    unsigned short* xb      = (unsigned short*)p; p += (size_t)M_PAD * F_IN * 2;    // slab
    unsigned short* Rbuf    = (unsigned short*)p; p += (size_t)N_NODES * 512 * 2;   // bf16 row-major
    unsigned short* wlin_f  = (unsigned short*)p; p += (size_t)D_H * F_IN * 2;
    const size_t WSZ = (size_t)L_LAYERS * T_ETYPES * D_H * D_H;  // 393216
    unsigned short* wpool_f = (unsigned short*)p; p += WSZ * 2;
    unsigned short* wself_f = (unsigned short*)p; p += WSZ * 2;
    unsigned short* wneigh_f= (unsigned short*)p; p += WSZ * 2;
    int* ip = (int*)p;
    const int NT = T_ETYPES * N_NODES;  // 40000
    int* cnt    = ip; ip += NT;
    int* incl   = ip; ip += NT;
    int* off    = ip; ip += NT + 1;
    int* cursor = ip; ip += NT;
    int* esrc   = ip; ip += T_ETYPES * E_EDGES;
    int* bsum   = ip; ip += 256;

    const dim3 blk(256);
    const dim3 blk512(512);
    const int E2 = T_ETYPES * E_EDGES;
    const dim3 e2grid((E2 + 255) / 256);
    const int nScanBlk = (NT + 255) / 256;  // 157

    // ---- cnt zero BEFORE prep (prep does the degree count) ----
    hipMemsetAsync(cnt, 0, (size_t)NT * sizeof(int), stream);

    // ---- prep: x->slab + weights->slab + count_deg, ONE dispatch ----
    {
        const int nx8  = M_PAD * F_IN / 8;          // 1,286,144
        const int nl8  = D_H * F_IN / 8;            // 16384
        const int nw8  = (int)(WSZ / 8);            // 49152
        const int tot  = nx8 + nl8 + 3 * nw8 + E2;
        prep_kernel<<<dim3((tot + 255) / 256), blk, 0, stream>>>(
            x, xb, nx8,
            Wlin, wlin_f, D_H, F_IN, nl8,
            Wpool, wpool_f, T_ETYPES * D_H, D_H, nw8,   // per layer: [512,256]
            Wself, wself_f, D_H, D_H, nw8,              // per (l,t): [256,256]
            Wneigh, wneigh_f, D_H, D_H, nw8,
            dst, cnt, E2);
    }

    // ---- CSR: scanA + scanC (scanB folded) + fill ----
    scanA_kernel<<<dim3(nScanBlk), blk, 0, stream>>>(cnt, incl, bsum, NT);
    scanC_kernel<<<dim3(nScanBlk), blk, 0, stream>>>(cnt, incl, bsum, off, cursor, NT, nScanBlk);
    fill_csr_kernel<<<e2grid, blk, 0, stream>>>(src, dst, cursor, esrc, E2);

    const int MGRP = (NBANDS + 7) / 8;  // 20 row-tile groups (padded)

    // ---- h0 = bf16(xb @ Wlin^T + blin), K=512, CS=2, slab out ----
    gemm_lds<16, 2, 1><<<dim3(MGRP * 16), blk512, 0, stream>>>(
        xb, wlin_f, blin, h_a, N_NODES, D_H, 0);

    unsigned short* h = h_a;
    unsigned short* hn = h_b;
    const dim3 sgrid((2 * N_NODES + 7) / 8);    // 5000
    const dim3 lngrid((N_NODES + 7) / 8);       // 2500
    for (int l = 0; l < L_LAYERS; ++l) {
        // hp = relu(h @ Wpool[l]^T + bpool[l]) row-major [N,512], both etypes, CS=4
        gemm_lds<8, 4, 0><<<dim3(MGRP * 32), blk512, 0, stream>>>(
            h, wpool_f + (size_t)l * T_ETYPES * D_H * D_H,
            bpool + (size_t)l * T_ETYPES * D_H, hp_b, N_NODES, T_ETYPES * D_H, 1);
        // neigh = segment_max per (node, t) -> slab
        seg_max_kernel<<<sgrid, blk512, 0, stream>>>(hp_b, off, esrc, neigh_b);
        // tail GEMM -> R bf16 (relu'd, bias'd), then LN+sum
        const size_t wlo = (size_t)l * T_ETYPES * D_H * D_H;
        const size_t blo = (size_t)l * T_ETYPES * D_H;
        if (l < L_LAYERS - 1) {
            tail_gemm<1><<<dim3(MGRP * 32), blk512, 0, stream>>>(
                h, neigh_b, wself_f + wlo, wneigh_f + wlo, bconv + blo, Rbuf);
            ln_sum_kernel<0><<<lngrid, blk512, 0, stream>>>(
                Rbuf, gamma + blo, beta + blo, hn);
        } else {
            tail_gemm<0><<<dim3(MGRP * 32), blk512, 0, stream>>>(
                h, neigh_b, wself_f + wlo, wneigh_f + wlo, bconv + blo, Rbuf);
            ln_sum_kernel<1><<<lngrid, blk512, 0, stream>>>(
                Rbuf, gamma + blo, beta + blo, d_out);
        }
        unsigned short* tmp = h; h = hn; hn = tmp;
    }
}